// Round 7
// baseline (441.271 us; speedup 1.0000x reference)
//
#include <hip/hip_runtime.h>
#include <hip/hip_bf16.h>
#include <math.h>

typedef __attribute__((ext_vector_type(8))) short short8;
typedef __attribute__((ext_vector_type(4))) float float4_t;
typedef __attribute__((ext_vector_type(2))) float cf2;   // complex (re, im) -> v_pk_* ops
typedef unsigned short ushort_t;
typedef unsigned int uint_t;

// Problem constants: B=8, C=256, L=2048, E=512, CH=4
#define NBL 16384          // B*L

// ---------------- workspace layout (bytes) ----------------
#define WS_CONVA   ((size_t)0)          // bf16 [512][768]  K reordered: k' = dk*256 + c
#define WS_WV      ((size_t)786432)     // bf16 [512][512]  Wv^T
#define WS_WO      ((size_t)1310720)    // bf16 [512][512]  Wo natural
#define WS_W1      ((size_t)1835008)    // bf16 [2048][512] s4_out_w^T
#define WS_WCAT    ((size_t)3932160)    // bf16 [512][256]
#define WS_A2      ((size_t)4194304)    // bf16 [512][512]  I + Wo@Wv
#define WS_ACOMB   ((size_t)4718592)    // bf16 FRAGMENT-major [s=k/32][h=m/64][im][lane][j] (2 MB)
#define WS_BCOMB   ((size_t)6815744)    // f32 [512]
#define WS_XN      ((size_t)6819840)    // bf16 [8][256][2048]
#define WS_H0PT    ((size_t)23597056)   // bf16 [16400][256]  padded x+orig, transposed
#define WS_U       ((size_t)31993856)   // bf16 [512][16384]  conv+gelu output h (ends 48771072)
#define WS_TW      ((size_t)48771072)   // cf2 [256][16] twiddle table exp(+i*2pi*p*j/4096) (32 KB, in U slack)
#define WS_UF      ((size_t)65548288)   // bf162 [2048][4096] u-pair spectra (32 MB, ends 99102720)
#define WS_KF      ((size_t)99102720)   // bf162 [2048][4096] kernel spectra (pre-scaled 1/4096)
#define WS_GTF     ((size_t)132657152)  // bf16 FRAGMENT-major g [s][nb][in][lane][j] (64 MB, ends 199766016)
#define WS_GATET   ((size_t)199766016)  // bf16 [16384][256]  (ends 208154624)
#define WS_UB      ((size_t)208162816)  // bf16-pair uint [512][8192]  LN output u, end 224940032

// ---------------- fast transcendental helpers ----------------
__device__ __forceinline__ float gelu_f(float x) {
    float t = x * x;
    float a2 = x * fmaf(0.07135481627f, t, 1.59576912161f);
    return x / (1.f + __expf(-a2));
}
__device__ __forceinline__ float tanh_f(float a) {
    return 1.f - 2.f / (1.f + __expf(2.f * a));
}
__device__ __forceinline__ float sigmoid_f(float b) {
    return 1.f / (1.f + __expf(-b));
}

__device__ __forceinline__ unsigned int pack_bf2(float a, float b) {
#if __has_builtin(__builtin_amdgcn_cvt_pk_bf16_f32)
    auto v = __builtin_amdgcn_cvt_pk_bf16_f32(a, b);
    unsigned int r; __builtin_memcpy(&r, &v, 4); return r;
#else
    __hip_bfloat16 ha = __float2bfloat16(a), hb = __float2bfloat16(b);
    unsigned short ua = *(unsigned short*)&ha, ub = *(unsigned short*)&hb;
    return (unsigned int)ua | ((unsigned int)ub << 16);
#endif
}
__device__ __forceinline__ ushort_t f2bfu(float a) {
    __hip_bfloat16 h = __float2bfloat16(a);
    return *(ushort_t*)&h;
}
__device__ __forceinline__ cf2 unpack_c(unsigned int v) {
    cf2 r;
    r.x = __uint_as_float(v << 16);
    r.y = __uint_as_float(v & 0xffff0000u);
    return r;
}
__device__ __forceinline__ float bf2f(ushort_t u) {
    return __uint_as_float(((unsigned int)u) << 16);
}

// async global->LDS 16B per lane. LDS dest is WAVE-UNIFORM base + lane*16 (m104);
// global src is per-lane.
__device__ __forceinline__ void cp16(const ushort_t* g, ushort_t* l) {
    __builtin_amdgcn_global_load_lds(
        (__attribute__((address_space(1))) void*)(void*)g,
        (__attribute__((address_space(3))) void*)l, 16, 0, 0);
}

// ---------------- packed complex primitives ----------------
__device__ __forceinline__ cf2 cswap(cf2 a) { return __builtin_shufflevector(a, a, 1, 0); }
template<int SGN>
__device__ __forceinline__ cf2 cmuli(cf2 a) {
    cf2 s = cswap(a);
    return s * cf2{(float)(-SGN), (float)SGN};
}
__device__ __forceinline__ cf2 cmul(cf2 a, cf2 b) {
    cf2 t = cswap(a) * cf2{-b.y, b.y};
    return a * cf2{b.x, b.x} + t;
}
__device__ __forceinline__ cf2 cmulc(cf2 a, float wr, float wi) {
    cf2 t = cswap(a) * cf2{-wi, wi};
    return a * cf2{wr, wr} + t;
}

// ============================ twiddle table: tw[p][j] = exp(+i*2pi*p*j/4096), p<256, j<16 ============
// Serves BOTH FFT stages of BOTH kernels: stage p*j/256 = tw[16p][j]; forward FFT conjugates.
// Replaces per-thread __sincosf + 15-deep serial cmul chains (tables identical across all blocks).
__global__ __launch_bounds__(256) void twprep_kernel(cf2* __restrict__ tw) {
    int t = threadIdx.x;
    #pragma unroll
    for (int j = 0; j < 16; ++j) {
        float s, c;
        sincosf(6.283185307179586f * (float)(t * j) * (1.f / 4096.f), &s, &c);
        tw[t * 16 + j] = cf2{c, s};
    }
}

// ============================ weight prep ============================
__global__ __launch_bounds__(256) void wprep_kernel(
    const float* __restrict__ conv_w, const float* __restrict__ attn_v_w,
    const float* __restrict__ attn_o_w, const float* __restrict__ s4_out_w,
    const float* __restrict__ res_w, const float* __restrict__ skip_w,
    __hip_bfloat16* __restrict__ convA, __hip_bfloat16* __restrict__ WvT,
    __hip_bfloat16* __restrict__ WoBf, __hip_bfloat16* __restrict__ W1T,
    __hip_bfloat16* __restrict__ Wcat)
{
    const int N0 = 393216, N1 = 655360, N2c = 917504, N3 = 1966080, N4 = 2097152;
    for (int i = blockIdx.x * 256 + threadIdx.x; i < N4; i += gridDim.x * 256) {
        if (i < N0) {
            int m = i / 768, r = i - m * 768, dk = r >> 8, c = r & 255;
            convA[i] = __float2bfloat16(conv_w[m * 768 + c * 3 + dk]);
        } else if (i < N1) {
            int j = i - N0; int row = j >> 9, e = j & 511;
            WvT[j] = __float2bfloat16(attn_v_w[e * 512 + row]);
        } else if (i < N2c) {
            WoBf[i - N1] = __float2bfloat16(attn_o_w[i - N1]);
        } else if (i < N3) {
            int j = i - N2c; int ck = j >> 9, e = j & 511;
            W1T[j] = __float2bfloat16(s4_out_w[e * 2048 + ck]);
        } else {
            int j = i - N3; int m = j >> 8, c = j & 255;
            float v = (m < 256) ? res_w[m * 256 + c] : skip_w[(m - 256) * 256 + c];
            Wcat[j] = __float2bfloat16(v);
        }
    }
}

__global__ __launch_bounds__(256) void bias2_kernel(
    const __hip_bfloat16* __restrict__ A2, const float* __restrict__ s4_out_b,
    const float* __restrict__ attn_o_w, const float* __restrict__ attn_v_b,
    const float* __restrict__ attn_o_b, float* __restrict__ bcomb)
{
    __shared__ float red[256];
    int o = blockIdx.x, t = threadIdx.x;
    float s = 0.f;
    for (int e = t; e < 512; e += 256)
        s += __bfloat162float(A2[o * 512 + e]) * s4_out_b[e] + attn_o_w[o * 512 + e] * attn_v_b[e];
    red[t] = s; __syncthreads();
    for (int k = 128; k > 0; k >>= 1) { if (t < k) red[t] += red[t + k]; __syncthreads(); }
    if (t == 0) bcomb[o] = red[0] + attn_o_b[o];
}

// ============================ prep: RMSNorm->xn bf16, (x+orig)->h0pT via LDS tile ============================
__global__ __launch_bounds__(512) void prep_kernel(
    const float* __restrict__ x, const float* __restrict__ orig,
    const float* __restrict__ sn, ushort_t* __restrict__ xnb, ushort_t* __restrict__ h0pT)
{
    __shared__ float red[8][64];
    __shared__ ushort_t T[256 * 66];
    int blk = blockIdx.x, t = threadIdx.x;
    int lane = t & 63, cg = t >> 6;
    int b = blk >> 5, l0 = (blk & 31) << 6;
    size_t basein = (size_t)b * 524288 + l0 + lane;
    float ss = 0.f;
    for (int c = cg; c < 256; c += 8) {
        size_t idx = basein + (size_t)c * 2048;
        float xv = x[idx], ov = orig[idx];
        ss += xv * xv;
        T[c * 66 + lane] = f2bfu(xv + ov);
    }
    red[cg][lane] = ss;
    __syncthreads();
    float tot = 0.f;
    #pragma unroll
    for (int k = 0; k < 8; ++k) tot += red[k][lane];
    float inv = 1.0f / (sqrtf(tot) * 0.0625f + 1e-8f);
    __hip_bfloat16* xo = (__hip_bfloat16*)xnb;
    for (int c = cg; c < 256; c += 8) {
        size_t idx = basein + (size_t)c * 2048;
        xo[idx] = __float2bfloat16(sn[c] * x[idx] * inv);
    }
    int c2 = t & 255, half = t >> 8;
    size_t rowbase = (size_t)(b * 2050 + 1 + l0);
    for (int r = half; r < 64; r += 2)
        h0pT[(rowbase + r) * 256 + c2] = T[c2 * 66 + r];
    if ((blk & 31) == 0) {
        if (t < 256) h0pT[(size_t)(b * 2050) * 256 + t] = 0;
        else         h0pT[(size_t)(b * 2050 + 2049) * 256 + (t - 256)] = 0;
    }
}

// ============================ LayerNorm over E: bf16 h -> pair-interleaved bf16 u ============================
// u stored as uint pairs: ushort idx = e*16384 + (b>>1)*4096 + 2*l + (b&1)
__global__ __launch_bounds__(512) void ln_kernel(
    const ushort_t* __restrict__ h, ushort_t* __restrict__ ub,
    const float* __restrict__ gam, const float* __restrict__ bet)
{
    __shared__ float r1[8][64], r2[8][64];
    int blk = blockIdx.x, t = threadIdx.x;
    int lane = t & 63, og = t >> 6;
    int n = (blk << 6) + lane;
    float s1 = 0.f, s2 = 0.f;
    for (int o = og; o < 512; o += 8) { float v = bf2f(h[(size_t)o * NBL + n]); s1 += v; s2 += v * v; }
    r1[og][lane] = s1; r2[og][lane] = s2;
    __syncthreads();
    float mu = 0.f, m2 = 0.f;
    #pragma unroll
    for (int k = 0; k < 8; ++k) { mu += r1[k][lane]; m2 += r2[k][lane]; }
    mu *= (1.f / 512.f); m2 *= (1.f / 512.f);
    float rstd = rsqrtf(m2 - mu * mu + 1e-5f);
    int b = n >> 11, l = n & 2047;
    size_t sbase = (size_t)(b >> 1) * 4096 + 2 * l + (b & 1);
    for (int o = og; o < 512; o += 8) {
        size_t idx = (size_t)o * NBL + n;
        ub[(size_t)o * 16384 + sbase] = f2bfu((bf2f(h[idx]) - mu) * rstd * gam[o] + bet[o]);
    }
}

// ============================ FFT: 4096-pt radix-16, LDS slot(i)=273B+17c+d ============================
#define PERM(m) ((((m) & 3) << 2) | ((m) >> 2))

template<int SGN>
__device__ __forceinline__ void dft4p(cf2& a0, cf2& a1, cf2& a2, cf2& a3) {
    cf2 t0 = a0 + a2, t1 = a0 - a2, t2 = a1 + a3, t3 = a1 - a3;
    cf2 j3 = cmuli<SGN>(t3);
    a0 = t0 + t2; a2 = t0 - t2;
    a1 = t1 + j3; a3 = t1 - j3;
}
template<int SGN>
__device__ __forceinline__ void dft4p_half(cf2& a0, cf2& a1, cf2& a2, cf2& a3) {
    cf2 u0 = a0, u1 = a1;
    cf2 j1 = cmuli<SGN>(u1);
    a0 = u0 + u1; a2 = u0 - u1;
    a1 = u0 + j1; a3 = u0 - j1;
}
template<int SGN>
__device__ __forceinline__ void dft4p_out01(cf2 a0, cf2 a1, cf2 a2, cf2 a3, cf2& o0, cf2& o1) {
    cf2 t0 = a0 + a2, t1 = a0 - a2, t2 = a1 + a3, t3 = a1 - a3;
    o0 = t0 + t2;
    o1 = t1 + cmuli<SGN>(t3);
}

template<int SGN>
__device__ __forceinline__ void dft16_stepB(cf2* x) {
    const float sg = (float)SGN;
    const float C16[10] = {1.f, 0.92387953f, 0.70710678f, 0.38268343f, 0.f,
                           -0.38268343f, -0.70710678f, -0.92387953f, -1.f, -0.92387953f};
    const float S16[10] = {0.f, 0.38268343f, 0.70710678f, 0.92387953f, 1.f,
                           0.92387953f, 0.70710678f, 0.38268343f, 0.f, -0.38268343f};
    #pragma unroll
    for (int s = 1; s < 4; ++s)
        #pragma unroll
        for (int r = 1; r < 4; ++r) {
            int e = s * r;
            x[4 * s + r] = cmulc(x[4 * s + r], C16[e], sg * S16[e]);
        }
}
template<int SGN>
__device__ __forceinline__ void dft16p(cf2* x) {
    #pragma unroll
    for (int r = 0; r < 4; ++r) dft4p<SGN>(x[r], x[4 + r], x[8 + r], x[12 + r]);
    dft16_stepB<SGN>(x);
    #pragma unroll
    for (int s = 0; s < 4; ++s) dft4p<SGN>(x[4 * s], x[4 * s + 1], x[4 * s + 2], x[4 * s + 3]);
}
template<int SGN>
__device__ __forceinline__ void dft16_halfin(cf2* x) {
    #pragma unroll
    for (int r = 0; r < 4; ++r) dft4p_half<SGN>(x[r], x[4 + r], x[8 + r], x[12 + r]);
    dft16_stepB<SGN>(x);
    #pragma unroll
    for (int s = 0; s < 4; ++s) dft4p<SGN>(x[4 * s], x[4 * s + 1], x[4 * s + 2], x[4 * s + 3]);
}
template<int SGN>
__device__ __forceinline__ void dft16_halfout(cf2* x, cf2* y) {
    #pragma unroll
    for (int r = 0; r < 4; ++r) dft4p<SGN>(x[r], x[4 + r], x[8 + r], x[12 + r]);
    dft16_stepB<SGN>(x);
    #pragma unroll
    for (int s = 0; s < 4; ++s)
        dft4p_out01<SGN>(x[4 * s], x[4 * s + 1], x[4 * s + 2], x[4 * s + 3], y[s], y[4 + s]);
}

// forward: wg<2048 -> packed u-pair rows (uint pair loads); wg>=2048 -> kernel rows (f32, pre-scale 1/4096)
// twiddles from table (conjugated: SGN=-1).
__global__ __launch_bounds__(256) void fft_fwd_kernel(
    const ushort_t* __restrict__ ubf, const float* __restrict__ s4k,
    const cf2* __restrict__ tw, uint4* __restrict__ uf, uint4* __restrict__ kf)
{
    __shared__ cf2 S[4368];
    int wg = blockIdx.x, t = threadIdx.x;
    // issue twiddle-row load early (used right after dft16_halfin)
    cf2 r2[16];
    #pragma unroll
    for (int j = 1; j < 16; ++j) r2[j] = tw[t * 16 + j];
    cf2 x[16];
    if (wg < 2048) {
        int bp = wg >> 9, e = wg & 511;
        const unsigned int* p0 = (const unsigned int*)ubf + (size_t)e * 8192 + (size_t)bp * 2048;
        #pragma unroll
        for (int j = 0; j < 8; ++j) x[j] = unpack_c(p0[j * 256 + t]);
    } else {
        const float* p0 = s4k + (size_t)(wg - 2048) * 2048;
        #pragma unroll
        for (int j = 0; j < 8; ++j) x[j] = cf2{p0[j * 256 + t], 0.f};
    }
    dft16_halfin<-1>(x);
    #pragma unroll
    for (int m = 1; m < 16; ++m) x[PERM(m)] = cmulc(x[PERM(m)], r2[m].x, -r2[m].y);
    int tb = 17 * (t >> 4) + (t & 15);
    #pragma unroll
    for (int m = 0; m < 16; ++m) S[tb + 273 * m] = x[PERM(m)];
    __syncthreads();
    int b2 = 273 * (t >> 4) + (t & 15);
    #pragma unroll
    for (int j = 0; j < 16; ++j) x[j] = S[b2 + 17 * j];
    dft16p<-1>(x);
    {
        const cf2* r1 = tw + 256 * (t & 15);     // row 16*(t&15): exp(i*2pi*(t&15)*m/256)
        #pragma unroll
        for (int m = 1; m < 16; ++m) { cf2 w = r1[m]; x[PERM(m)] = cmulc(x[PERM(m)], w.x, -w.y); }
    }
    #pragma unroll
    for (int m = 0; m < 16; ++m) S[b2 + 17 * m] = x[PERM(m)];
    __syncthreads();
    int b3 = 273 * (t >> 4) + 17 * (t & 15);
    #pragma unroll
    for (int j = 0; j < 16; ++j) x[j] = S[b3 + j];
    dft16p<-1>(x);
    const float sc = (wg < 2048) ? 1.f : (1.f / 4096.f);
    uint4* dst = ((wg < 2048) ? (uf + (size_t)wg * 1024) : (kf + (size_t)(wg - 2048) * 1024)) + 4 * t;
    #pragma unroll
    for (int q = 0; q < 4; ++q) {
        uint4 o;
        cf2 v0 = x[PERM(4 * q)] * sc, v1 = x[PERM(4 * q + 1)] * sc;
        cf2 v2 = x[PERM(4 * q + 2)] * sc, v3 = x[PERM(4 * q + 3)] * sc;
        o.x = pack_bf2(v0.x, v0.y);
        o.y = pack_bf2(v1.x, v1.y);
        o.z = pack_bf2(v2.x, v2.y);
        o.w = pack_bf2(v3.x, v3.y);
        dst[q] = o;
    }
}

// ============================ fft_inv FUSED with gdt ============================
// spectra product in registers, DIT stages, half-out; then (fused) D-skip + gelu + fragment-major
// store of g directly from registers. Twiddles from table (SGN=+1, direct). XCD-chunked decode.
__global__ __launch_bounds__(256) void fft_inv_kernel(
    const uint4* __restrict__ uf, const uint4* __restrict__ kf,
    const unsigned int* __restrict__ ub2, const float* __restrict__ s4D,
    const cf2* __restrict__ tw, ushort_t* __restrict__ gT)
{
    __shared__ cf2 S[4368];
    int bid = blockIdx.x, t = threadIdx.x;
    int tau = (bid & 7) * 1024 + (bid >> 3);      // bijective, 8192 % 8 == 0
    int e = tau >> 4, ch = (tau >> 2) & 3, bp = tau & 3;
    int r = ch * 512 + e;
    // issue the stage-3 twiddle row early: ~2 dft16p of cover before first use
    cf2 r2[16];
    #pragma unroll
    for (int j = 1; j < 16; ++j) r2[j] = tw[t * 16 + j];
    const uint4* zr = uf + (size_t)(bp * 512 + e) * 1024 + 4 * t;
    const uint4* kr = kf + (size_t)(ch * 512 + e) * 1024 + 4 * t;
    cf2 x[16];
    #pragma unroll
    for (int q = 0; q < 4; ++q) {
        uint4 a4 = zr[q], b4 = kr[q];
        x[4 * q + 0] = cmul(unpack_c(a4.x), unpack_c(b4.x));
        x[4 * q + 1] = cmul(unpack_c(a4.y), unpack_c(b4.y));
        x[4 * q + 2] = cmul(unpack_c(a4.z), unpack_c(b4.z));
        x[4 * q + 3] = cmul(unpack_c(a4.w), unpack_c(b4.w));
    }
    dft16p<1>(x);
    int b1 = 273 * (t >> 4) + 17 * (t & 15);
    #pragma unroll
    for (int m = 0; m < 16; ++m) S[b1 + m] = x[PERM(m)];
    __syncthreads();
    int b2 = 273 * (t >> 4) + (t & 15);
    #pragma unroll
    for (int j = 0; j < 16; ++j) x[j] = S[b2 + 17 * j];
    {
        const cf2* r1 = tw + 256 * (t & 15);     // row 16*(t&15): exp(i*2pi*(t&15)*j/256)
        #pragma unroll
        for (int j = 1; j < 16; ++j) { cf2 w = r1[j]; x[j] = cmulc(x[j], w.x, w.y); }
    }
    dft16p<1>(x);
    #pragma unroll
    for (int m = 0; m < 16; ++m) S[b2 + 17 * m] = x[PERM(m)];
    __syncthreads();
    int b3 = 17 * (t >> 4) + (t & 15);
    #pragma unroll
    for (int j = 0; j < 16; ++j) x[j] = S[b3 + 273 * j];
    #pragma unroll
    for (int j = 1; j < 16; ++j) x[j] = cmulc(x[j], r2[j].x, r2[j].y);
    cf2 y[8];
    dft16_halfout<1>(x, y);

    // ---- fused gdt: y + D*u, gelu, fragment-major store (same index formula as old gdt) ----
    const float d = s4D[r];
    const unsigned int* ur = ub2 + (size_t)e * 8192 + (size_t)bp * 2048 + t;
    const size_t rpart = (size_t)(r >> 5) * 524288 + (size_t)(((r >> 3) & 3) * 128 + (r & 7));
    #pragma unroll
    for (int m = 0; m < 8; ++m) {
        int l = m * 256 + t;
        cf2 u2 = unpack_c(ur[m * 256]);
        float v0 = gelu_f(fmaf(d, u2.x, y[m].x));
        float v1 = gelu_f(fmaf(d, u2.y, y[m].y));
        int n_lo = bp * 4096 + l;                 // batch 2bp at position l; n_hi = n_lo + 2048
        size_t npart = (size_t)(n_lo >> 6) * 2048 + (size_t)(((n_lo >> 4) & 3) * 512 + (n_lo & 15) * 8);
        gT[rpart + npart]         = f2bfu(v0);
        gT[rpart + npart + 65536] = f2bfu(v1);    // +2048 in n -> +32*2048 ushorts
    }
}

// ============================ gemmF: EPI5 fragment-direct GEMM — no LDS, no barriers in K-loop ============
// Operands pre-stored fragment-major (Acomb via EPI2 epilogue, g via fused fft_inv): each lane loads its
// MFMA fragment as one coalesced global_load_dwordx4 from L2/L3. Depth-2 register pipeline.
__global__ __launch_bounds__(256) void gemmF_kernel(
    const ushort_t* __restrict__ Af, const ushort_t* __restrict__ Bf,
    ushort_t* __restrict__ Cb, const float* __restrict__ bias)
{
    __shared__ ushort_t SM[8704];                    // epilogue gate tile [128][68] only
    const int t = threadIdx.x;
    const int w = t >> 6, lane = t & 63, quad = lane >> 4, lr = lane & 15;
    const int wm = (w >> 1) * 64;
    const int by = blockIdx.y, n0 = blockIdx.x * 128;
    const int h = (w >> 1) ? (4 + by) : by;          // A row-block: rows {64by..} / {256+64by..}
    const int nb = (n0 >> 6) + (w & 1);              // B col-block of 64

    const ushort_t* Aw = Af + (size_t)h * 2048 + (size_t)lane * 8;   // + s*16384 + im*512
    const ushort_t* Bw = Bf + (size_t)nb * 2048 + (size_t)lane * 8;  // + s*524288 + in*512

    float4_t acc[4][4];
    #pragma unroll
    for (int i = 0; i < 4; ++i)
        #pragma unroll
        for (int j = 0; j < 4; ++j) { float4_t z = {0.f, 0.f, 0.f, 0.f}; acc[i][j] = z; }

    short8 a0[4], a1[4], b0[4], b1[4];

#define LDA(D, S) do { _Pragma("unroll") for (int i_ = 0; i_ < 4; ++i_) \
        D[i_] = *(const short8*)(Aw + (size_t)(S) * 16384 + i_ * 512); } while (0)
#define LDB(D, S) do { _Pragma("unroll") for (int i_ = 0; i_ < 4; ++i_) \
        D[i_] = *(const short8*)(Bw + (size_t)(S) * 524288 + i_ * 512); } while (0)
#define CMP(AA, BB) do { _Pragma("unroll") for (int im_ = 0; im_ < 4; ++im_) \
        _Pragma("unroll") for (int in_ = 0; in_ < 4; ++in_) \
            acc[im_][in_] = __builtin_amdgcn_mfma_f32_16x16x32_bf16(AA[im_], BB[in_], acc[im_][in_], 0, 0, 0); } while (0)

    LDA(a0, 0); LDB(b0, 0);
    LDA(a1, 1); LDB(b1, 1);
    for (int s = 0; s < 64; s += 2) {                // K = 2048 fixed -> 64 steps of 32
        CMP(a0, b0);
        if (s + 2 < 64) { LDA(a0, s + 2); LDB(b0, s + 2); }
        CMP(a1, b1);
        if (s + 3 < 64) { LDA(a1, s + 3); LDB(b1, s + 3); }
    }
#undef LDA
#undef LDB
#undef CMP

    // ---- gate-fused epilogue (identical math to previous EPI5) ----
    #pragma unroll
    for (int p = 0; p < 2; ++p) {
        if (p) __syncthreads();
        if ((w & 1) == p) {                          // waves owning this n-half
            #pragma unroll
            for (int im = 0; im < 4; ++im)
                #pragma unroll
                for (int in_ = 0; in_ < 4; ++in_) {
                    int nl = in_ * 16 + lr;
                    #pragma unroll
                    for (int r = 0; r < 4; ++r) {
                        int i = wm + im * 16 + quad * 4 + r;
                        int me = (i < 64) ? (64 * by + i) : (192 + 64 * by + i);
                        SM[i * 68 + nl] = f2bfu(acc[im][in_][r] + bias[me]);
                    }
                }
        }
        __syncthreads();
        int nl = t >> 2, gcb = (t & 3) * 16;
        size_t obase = (size_t)(n0 + 64 * p + nl) * 256 + 64 * by + gcb;
        short8 o0, o1;
        #pragma unroll
        for (int j = 0; j < 16; ++j) {
            int gc = gcb + j;
            float a = bf2f(SM[gc * 68 + nl]);
            float bb = bf2f(SM[(gc + 64) * 68 + nl]);
            ushort_t gv = f2bfu(tanh_f(a) * sigmoid_f(bb));
            if (j < 8) o0[j] = (short)gv; else o1[j - 8] = (short)gv;
        }
        *(short8*)(Cb + obase) = o0;
        *(short8*)(Cb + obase + 8) = o1;
    }
}

// ============================ gemm: 128Mx64N tile, global_load_lds, static dbuf (round-3) ============================
// Used for the short-K gemms (conv K=768, EPI4 K=256, prep K=512). EPI2 writes its output
// (Acomb) in A-FRAGMENT-major layout for gemmF.
template<int BSRC, int EPI>
__global__ __launch_bounds__(256, 4) void gemm_kernel(
    const ushort_t* __restrict__ A, const ushort_t* __restrict__ Bm,
    ushort_t* __restrict__ Cb, float* __restrict__ Cf,
    int M, int N, int K,
    const float* __restrict__ bias, const float* __restrict__ bias2,
    const ushort_t* __restrict__ xnb, float* __restrict__ dout)
{
    __shared__ ushort_t SM[16384];       // 2 x 8192 (32 KB)
    const int t = threadIdx.x;
    const int n0 = blockIdx.x * 64, m0 = blockIdx.y * 128;
    const int w = t >> 6, lane = t & 63, quad = lane >> 4, lr = lane & 15;
    const int wm = (w >> 1) * 64, wn = (w & 1) * 32;

    // ---- staging geometry ----
    const int srow = lane >> 2;                              // row within 16-row issue group
    const int swslot = ((lane & 3) ^ ((lane >> 3) & 3)) * 8; // pre-swizzled col slot (ushorts)
    const int r0q = w * 32 + srow;                           // A q=0 tile-row; q=1 adds 16
    int ar0 = m0 + r0q, ar1 = m0 + r0q + 16;
    const ushort_t* aSrc0 = A + (size_t)ar0 * K + swslot;
    const ushort_t* aSrc1 = A + (size_t)ar1 * K + swslot;
    const int nrow = n0 + w * 16 + srow;                     // B tile-row (one issue/wave)
    const ushort_t* bSrc;
    if (BSRC == 0) bSrc = Bm + (size_t)nrow * K + swslot;
    else           bSrc = Bm + (size_t)((nrow >> 11) * 2050 + (nrow & 2047)) * 256 + swslot;

    // wave-uniform LDS dest offsets within a buffer (ushort units; lane*16B added by HW)
    const int aD = w * 1024;             // A region [0,4096)
    const int bD = 4096 + w * 512;       // B region [4096,6144)

    float4_t acc[4][2];
    #pragma unroll
    for (int i = 0; i < 4; ++i)
        #pragma unroll
        for (int j = 0; j < 2; ++j) { float4_t z = {0.f, 0.f, 0.f, 0.f}; acc[i][j] = z; }

    const int qsw = (quad ^ ((lr >> 1) & 3)) << 3;           // read-side swizzled slot (ushorts)

#define STAGE(BUF, KK) do {                                                     \
        cp16(aSrc0 + (KK), SM + (BUF) + aD);                                    \
        cp16(aSrc1 + (KK), SM + (BUF) + aD + 512);                              \
        if (BSRC == 0) cp16(bSrc + (KK), SM + (BUF) + bD);                      \
        else cp16(bSrc + (((KK) >> 8) * 256 + ((KK) & 255)), SM + (BUF) + bD);  \
    } while (0)

#define COMPUTE(BUF) do {                                                       \
        const ushort_t* Al = SM + (BUF);                                        \
        const ushort_t* Bl = SM + (BUF) + 4096;                                 \
        short8 af[4], bfr[2];                                                   \
        _Pragma("unroll")                                                       \
        for (int im = 0; im < 4; ++im)                                          \
            af[im] = *(const short8*)&Al[(wm + im * 16 + lr) * 32 + qsw];       \
        _Pragma("unroll")                                                       \
        for (int in_ = 0; in_ < 2; ++in_)                                       \
            bfr[in_] = *(const short8*)&Bl[(wn + in_ * 16 + lr) * 32 + qsw];    \
        _Pragma("unroll")                                                       \
        for (int im = 0; im < 4; ++im)                                          \
            _Pragma("unroll")                                                   \
            for (int in_ = 0; in_ < 2; ++in_)                                   \
                acc[im][in_] = __builtin_amdgcn_mfma_f32_16x16x32_bf16(         \
                    af[im], bfr[in_], acc[im][in_], 0, 0, 0);                   \
    } while (0)

    // prologue: stage K-tile 0 into buffer 0
    STAGE(0, 0);
    __syncthreads();                             // drains vmcnt(0): tile 0 ready

    for (int kt = 0; kt < K; kt += 64) {         // K % 64 == 0 for all instantiations
        STAGE(8192, kt + 32);                    // prefetch odd tile into buf1
        COMPUTE(0);
        __syncthreads();                         // buf1 ready; buf0 reads done
        if (kt + 64 < K) STAGE(0, kt + 64);      // prefetch next even tile into buf0
        COMPUTE(8192);
        __syncthreads();                         // buf0 ready; buf1 reads done
    }
#undef STAGE
#undef COMPUTE

    #pragma unroll
    for (int im = 0; im < 4; ++im) {
        #pragma unroll
        for (int in_ = 0; in_ < 2; ++in_) {
            int n = n0 + wn + in_ * 16 + lr;
            int mb = m0 + wm + im * 16 + quad * 4;
            #pragma unroll
            for (int r = 0; r < 4; ++r) {
                int m = mb + r;
                float v = acc[im][in_][r];
                if (EPI == 0) {
                    v += bias[m];
                    ((__hip_bfloat16*)Cb)[(size_t)m * N + n] = __float2bfloat16(gelu_f(v));
                } else if (EPI == 1) {
                    v += (m == n) ? 1.0f : 0.0f;
                    ((__hip_bfloat16*)Cb)[(size_t)m * N + n] = __float2bfloat16(v);
                } else if (EPI == 2) {
                    // A-fragment-major write for gemmF:
                    // idx16 = ((s*8 + h)*4 + im)*64 + quad*16 + lr ; ushort = idx16*8 + j
                    size_t fi = ((((size_t)(n >> 5) * 8 + (m >> 6)) * 4 + ((m >> 4) & 3)) * 64
                                 + ((n >> 3) & 3) * 16 + (m & 15)) * 8 + (n & 7);
                    Cb[fi] = f2bfu(v);
                } else {
                    int bb = n >> 11, ll = n & 2047;
                    if (m < 256) {
                        v += bias[m];
                        int idx = (bb << 19) + (m << 11) + ll;
                        dout[idx] = (bf2f(xnb[idx]) + v) * 0.70710678118654752f;
                    } else {
                        v += bias2[m - 256];
                        dout[4194304 + (bb << 19) + ((m - 256) << 11) + ll] = v;
                    }
                }
            }
        }
    }
}

// ============================ launch ============================
extern "C" void kernel_launch(void* const* d_in, const int* in_sizes, int n_in,
                              void* d_out, int out_size, void* d_ws, size_t ws_size,
                              hipStream_t stream)
{
    const float* x         = (const float*)d_in[0];
    const float* original  = (const float*)d_in[1];
    const float* sn_scale  = (const float*)d_in[2];
    const float* conv_w    = (const float*)d_in[3];
    const float* conv_b    = (const float*)d_in[4];
    const float* s4_ln_g   = (const float*)d_in[5];
    const float* s4_ln_b   = (const float*)d_in[6];
    const float* s4_kernel = (const float*)d_in[7];
    const float* s4_D      = (const float*)d_in[8];
    const float* s4_out_w  = (const float*)d_in[9];
    const float* s4_out_b  = (const float*)d_in[10];
    const float* attn_v_w  = (const float*)d_in[11];
    const float* attn_v_b  = (const float*)d_in[12];
    const float* attn_o_w  = (const float*)d_in[13];
    const float* attn_o_b  = (const float*)d_in[14];
    const float* res_w     = (const float*)d_in[15];
    const float* res_b     = (const float*)d_in[16];
    const float* skip_w    = (const float*)d_in[17];
    const float* skip_b    = (const float*)d_in[18];

    char* ws = (char*)d_ws;
    __hip_bfloat16* convA = (__hip_bfloat16*)(ws + WS_CONVA);
    __hip_bfloat16* WvT   = (__hip_bfloat16*)(ws + WS_WV);
    __hip_bfloat16* WoBf  = (__hip_bfloat16*)(ws + WS_WO);
    __hip_bfloat16* W1T   = (__hip_bfloat16*)(ws + WS_W1);
    __hip_bfloat16* Wcat  = (__hip_bfloat16*)(ws + WS_WCAT);
    ushort_t* A2    = (ushort_t*)(ws + WS_A2);
    ushort_t* Acomb = (ushort_t*)(ws + WS_ACOMB);
    float* bcombp  = (float*)(ws + WS_BCOMB);
    ushort_t* xnb  = (ushort_t*)(ws + WS_XN);
    ushort_t* h0pT = (ushort_t*)(ws + WS_H0PT);
    ushort_t* hP   = (ushort_t*)(ws + WS_U);
    cf2* twP   = (cf2*)(ws + WS_TW);
    ushort_t* ubP  = (ushort_t*)(ws + WS_UB);
    uint4* ufP = (uint4*)(ws + WS_UF);
    uint4* kfP = (uint4*)(ws + WS_KF);
    ushort_t* gT    = (ushort_t*)(ws + WS_GTF);
    ushort_t* gateT = (ushort_t*)(ws + WS_GATET);

    // weight prep + attention-fold precompute
    wprep_kernel<<<dim3(4096), dim3(256), 0, stream>>>(conv_w, attn_v_w, attn_o_w, s4_out_w,
        res_w, skip_w, convA, WvT, WoBf, W1T, Wcat);
    twprep_kernel<<<dim3(1), dim3(256), 0, stream>>>(twP);
    gemm_kernel<0, 1><<<dim3(8, 4), dim3(256), 0, stream>>>(
        (const ushort_t*)WoBf, (const ushort_t*)WvT, A2, nullptr, 512, 512, 512,
        nullptr, nullptr, nullptr, nullptr);
    bias2_kernel<<<dim3(512), dim3(256), 0, stream>>>(
        (const __hip_bfloat16*)A2, s4_out_b, attn_o_w, attn_v_b, attn_o_b, bcombp);
    gemm_kernel<0, 2><<<dim3(32, 4), dim3(256), 0, stream>>>(
        A2, (const ushort_t*)W1T, Acomb, nullptr, 512, 2048, 512,
        nullptr, nullptr, nullptr, nullptr);

    // main pipeline
    prep_kernel<<<dim3(256), dim3(512), 0, stream>>>(x, original, sn_scale, xnb, h0pT);
    gemm_kernel<1, 0><<<dim3(256, 4), dim3(256), 0, stream>>>(
        (const ushort_t*)convA, h0pT, hP, nullptr, 512, NBL, 768,
        conv_b, nullptr, nullptr, nullptr);
    ln_kernel<<<dim3(256), dim3(512), 0, stream>>>(hP, ubP, s4_ln_g, s4_ln_b);
    fft_fwd_kernel<<<dim3(4096), dim3(256), 0, stream>>>(ubP, s4_kernel, twP, ufP, kfP);
    fft_inv_kernel<<<dim3(8192), dim3(256), 0, stream>>>(
        ufP, kfP, (const unsigned int*)ubP, s4_D, twP, gT);
    gemmF_kernel<<<dim3(128, 4), dim3(256), 0, stream>>>(
        (const ushort_t*)Acomb, gT, gateT, bcombp);
    gemm_kernel<0, 4><<<dim3(256, 4), dim3(256), 0, stream>>>(
        (const ushort_t*)Wcat, gateT, nullptr, nullptr, 512, NBL, 256,
        res_b, skip_b, xnb, (float*)d_out);
}

// Round 8
// 386.130 us; speedup vs baseline: 1.1428x; 1.1428x over previous
//
#include <hip/hip_runtime.h>
#include <hip/hip_bf16.h>
#include <math.h>

typedef __attribute__((ext_vector_type(8))) short short8;
typedef __attribute__((ext_vector_type(4))) float float4_t;
typedef __attribute__((ext_vector_type(2))) float cf2;   // complex (re, im) -> v_pk_* ops
typedef unsigned short ushort_t;
typedef unsigned int uint_t;

// Problem constants: B=8, C=256, L=2048, E=512, CH=4
#define NBL 16384          // B*L

// ---------------- workspace layout (bytes) ----------------
#define WS_CONVA   ((size_t)0)          // bf16 [512][768]  K reordered: k' = dk*256 + c
#define WS_WV      ((size_t)786432)     // bf16 [512][512]  Wv^T
#define WS_WO      ((size_t)1310720)    // bf16 [512][512]  Wo natural
#define WS_W1      ((size_t)1835008)    // bf16 [2048][512] s4_out_w^T
#define WS_WCAT    ((size_t)3932160)    // bf16 [512][256]
#define WS_A2      ((size_t)4194304)    // bf16 [512][512]  I + Wo@Wv
#define WS_ACOMB   ((size_t)4718592)    // bf16 FRAGMENT-major [s=k/32][h=m/64][im][lane][j] (2 MB)
#define WS_BCOMB   ((size_t)6815744)    // f32 [512]
#define WS_XN      ((size_t)6819840)    // bf16 [8][256][2048]
#define WS_H0PT    ((size_t)23597056)   // bf16 [16400][256]  padded x+orig, transposed
#define WS_U       ((size_t)31993856)   // bf16 [512][16384]  conv+gelu output h
#define WS_UF      ((size_t)65548288)   // bf162 [2048][4096] u-pair spectra (32 MB, ends 99102720)
#define WS_KF      ((size_t)99102720)   // bf162 [2048][4096] kernel spectra (pre-scaled 1/4096)
#define WS_GTF     ((size_t)132657152)  // bf16 FRAGMENT-major g [s][nb][in][lane][j] (64 MB, ends 199766016)
#define WS_GATET   ((size_t)199766016)  // bf16 [16384][256]  (ends 208154624)
#define WS_UB      ((size_t)208162816)  // bf16-pair uint [512][8192]  LN output u, end 224940032

// ---------------- fast transcendental helpers ----------------
__device__ __forceinline__ float gelu_f(float x) {
    float t = x * x;
    float a2 = x * fmaf(0.07135481627f, t, 1.59576912161f);
    return x / (1.f + __expf(-a2));
}
__device__ __forceinline__ float tanh_f(float a) {
    return 1.f - 2.f / (1.f + __expf(2.f * a));
}
__device__ __forceinline__ float sigmoid_f(float b) {
    return 1.f / (1.f + __expf(-b));
}

__device__ __forceinline__ unsigned int pack_bf2(float a, float b) {
#if __has_builtin(__builtin_amdgcn_cvt_pk_bf16_f32)
    auto v = __builtin_amdgcn_cvt_pk_bf16_f32(a, b);
    unsigned int r; __builtin_memcpy(&r, &v, 4); return r;
#else
    __hip_bfloat16 ha = __float2bfloat16(a), hb = __float2bfloat16(b);
    unsigned short ua = *(unsigned short*)&ha, ub = *(unsigned short*)&hb;
    return (unsigned int)ua | ((unsigned int)ub << 16);
#endif
}
__device__ __forceinline__ ushort_t f2bfu(float a) {
    __hip_bfloat16 h = __float2bfloat16(a);
    return *(ushort_t*)&h;
}
__device__ __forceinline__ cf2 unpack_c(unsigned int v) {
    cf2 r;
    r.x = __uint_as_float(v << 16);
    r.y = __uint_as_float(v & 0xffff0000u);
    return r;
}
__device__ __forceinline__ float bf2f(ushort_t u) {
    return __uint_as_float(((unsigned int)u) << 16);
}

// async global->LDS 16B per lane. LDS dest is WAVE-UNIFORM base + lane*16 (m104);
// global src is per-lane.
__device__ __forceinline__ void cp16(const ushort_t* g, ushort_t* l) {
    __builtin_amdgcn_global_load_lds(
        (__attribute__((address_space(1))) void*)(void*)g,
        (__attribute__((address_space(3))) void*)l, 16, 0, 0);
}

// ---------------- packed complex primitives ----------------
__device__ __forceinline__ cf2 cswap(cf2 a) { return __builtin_shufflevector(a, a, 1, 0); }
template<int SGN>
__device__ __forceinline__ cf2 cmuli(cf2 a) {
    cf2 s = cswap(a);
    return s * cf2{(float)(-SGN), (float)SGN};
}
__device__ __forceinline__ cf2 cmul(cf2 a, cf2 b) {
    cf2 t = cswap(a) * cf2{-b.y, b.y};
    return a * cf2{b.x, b.x} + t;
}
__device__ __forceinline__ cf2 cmulc(cf2 a, float wr, float wi) {
    cf2 t = cswap(a) * cf2{-wi, wi};
    return a * cf2{wr, wr} + t;
}

// ============================ weight prep ============================
__global__ __launch_bounds__(256) void wprep_kernel(
    const float* __restrict__ conv_w, const float* __restrict__ attn_v_w,
    const float* __restrict__ attn_o_w, const float* __restrict__ s4_out_w,
    const float* __restrict__ res_w, const float* __restrict__ skip_w,
    __hip_bfloat16* __restrict__ convA, __hip_bfloat16* __restrict__ WvT,
    __hip_bfloat16* __restrict__ WoBf, __hip_bfloat16* __restrict__ W1T,
    __hip_bfloat16* __restrict__ Wcat)
{
    const int N0 = 393216, N1 = 655360, N2c = 917504, N3 = 1966080, N4 = 2097152;
    for (int i = blockIdx.x * 256 + threadIdx.x; i < N4; i += gridDim.x * 256) {
        if (i < N0) {
            int m = i / 768, r = i - m * 768, dk = r >> 8, c = r & 255;
            convA[i] = __float2bfloat16(conv_w[m * 768 + c * 3 + dk]);
        } else if (i < N1) {
            int j = i - N0; int row = j >> 9, e = j & 511;
            WvT[j] = __float2bfloat16(attn_v_w[e * 512 + row]);
        } else if (i < N2c) {
            WoBf[i - N1] = __float2bfloat16(attn_o_w[i - N1]);
        } else if (i < N3) {
            int j = i - N2c; int ck = j >> 9, e = j & 511;
            W1T[j] = __float2bfloat16(s4_out_w[e * 2048 + ck]);
        } else {
            int j = i - N3; int m = j >> 8, c = j & 255;
            float v = (m < 256) ? res_w[m * 256 + c] : skip_w[(m - 256) * 256 + c];
            Wcat[j] = __float2bfloat16(v);
        }
    }
}

__global__ __launch_bounds__(256) void bias2_kernel(
    const __hip_bfloat16* __restrict__ A2, const float* __restrict__ s4_out_b,
    const float* __restrict__ attn_o_w, const float* __restrict__ attn_v_b,
    const float* __restrict__ attn_o_b, float* __restrict__ bcomb)
{
    __shared__ float red[256];
    int o = blockIdx.x, t = threadIdx.x;
    float s = 0.f;
    for (int e = t; e < 512; e += 256)
        s += __bfloat162float(A2[o * 512 + e]) * s4_out_b[e] + attn_o_w[o * 512 + e] * attn_v_b[e];
    red[t] = s; __syncthreads();
    for (int k = 128; k > 0; k >>= 1) { if (t < k) red[t] += red[t + k]; __syncthreads(); }
    if (t == 0) bcomb[o] = red[0] + attn_o_b[o];
}

// ============================ prep: RMSNorm->xn bf16, (x+orig)->h0pT via LDS tile ============================
__global__ __launch_bounds__(512) void prep_kernel(
    const float* __restrict__ x, const float* __restrict__ orig,
    const float* __restrict__ sn, ushort_t* __restrict__ xnb, ushort_t* __restrict__ h0pT)
{
    __shared__ float red[8][64];
    __shared__ ushort_t T[256 * 66];
    int blk = blockIdx.x, t = threadIdx.x;
    int lane = t & 63, cg = t >> 6;
    int b = blk >> 5, l0 = (blk & 31) << 6;
    size_t basein = (size_t)b * 524288 + l0 + lane;
    float ss = 0.f;
    for (int c = cg; c < 256; c += 8) {
        size_t idx = basein + (size_t)c * 2048;
        float xv = x[idx], ov = orig[idx];
        ss += xv * xv;
        T[c * 66 + lane] = f2bfu(xv + ov);
    }
    red[cg][lane] = ss;
    __syncthreads();
    float tot = 0.f;
    #pragma unroll
    for (int k = 0; k < 8; ++k) tot += red[k][lane];
    float inv = 1.0f / (sqrtf(tot) * 0.0625f + 1e-8f);
    __hip_bfloat16* xo = (__hip_bfloat16*)xnb;
    for (int c = cg; c < 256; c += 8) {
        size_t idx = basein + (size_t)c * 2048;
        xo[idx] = __float2bfloat16(sn[c] * x[idx] * inv);
    }
    int c2 = t & 255, half = t >> 8;
    size_t rowbase = (size_t)(b * 2050 + 1 + l0);
    for (int r = half; r < 64; r += 2)
        h0pT[(rowbase + r) * 256 + c2] = T[c2 * 66 + r];
    if ((blk & 31) == 0) {
        if (t < 256) h0pT[(size_t)(b * 2050) * 256 + t] = 0;
        else         h0pT[(size_t)(b * 2050 + 2049) * 256 + (t - 256)] = 0;
    }
}

// ============================ LayerNorm over E: bf16 h -> pair-interleaved bf16 u ============================
// u stored as uint pairs: ushort idx = e*16384 + (b>>1)*4096 + 2*l + (b&1)
__global__ __launch_bounds__(512) void ln_kernel(
    const ushort_t* __restrict__ h, ushort_t* __restrict__ ub,
    const float* __restrict__ gam, const float* __restrict__ bet)
{
    __shared__ float r1[8][64], r2[8][64];
    int blk = blockIdx.x, t = threadIdx.x;
    int lane = t & 63, og = t >> 6;
    int n = (blk << 6) + lane;
    float s1 = 0.f, s2 = 0.f;
    for (int o = og; o < 512; o += 8) { float v = bf2f(h[(size_t)o * NBL + n]); s1 += v; s2 += v * v; }
    r1[og][lane] = s1; r2[og][lane] = s2;
    __syncthreads();
    float mu = 0.f, m2 = 0.f;
    #pragma unroll
    for (int k = 0; k < 8; ++k) { mu += r1[k][lane]; m2 += r2[k][lane]; }
    mu *= (1.f / 512.f); m2 *= (1.f / 512.f);
    float rstd = rsqrtf(m2 - mu * mu + 1e-5f);
    int b = n >> 11, l = n & 2047;
    size_t sbase = (size_t)(b >> 1) * 4096 + 2 * l + (b & 1);
    for (int o = og; o < 512; o += 8) {
        size_t idx = (size_t)o * NBL + n;
        ub[(size_t)o * 16384 + sbase] = f2bfu((bf2f(h[idx]) - mu) * rstd * gam[o] + bet[o]);
    }
}

// ============================ FFT: 4096-pt radix-16, LDS slot(i)=273B+17c+d ============================
#define PERM(m) ((((m) & 3) << 2) | ((m) >> 2))

template<int SGN>
__device__ __forceinline__ void dft4p(cf2& a0, cf2& a1, cf2& a2, cf2& a3) {
    cf2 t0 = a0 + a2, t1 = a0 - a2, t2 = a1 + a3, t3 = a1 - a3;
    cf2 j3 = cmuli<SGN>(t3);
    a0 = t0 + t2; a2 = t0 - t2;
    a1 = t1 + j3; a3 = t1 - j3;
}
template<int SGN>
__device__ __forceinline__ void dft4p_half(cf2& a0, cf2& a1, cf2& a2, cf2& a3) {
    cf2 u0 = a0, u1 = a1;
    cf2 j1 = cmuli<SGN>(u1);
    a0 = u0 + u1; a2 = u0 - u1;
    a1 = u0 + j1; a3 = u0 - j1;
}
template<int SGN>
__device__ __forceinline__ void dft4p_out01(cf2 a0, cf2 a1, cf2 a2, cf2 a3, cf2& o0, cf2& o1) {
    cf2 t0 = a0 + a2, t1 = a0 - a2, t2 = a1 + a3, t3 = a1 - a3;
    o0 = t0 + t2;
    o1 = t1 + cmuli<SGN>(t3);
}

template<int SGN>
__device__ __forceinline__ void dft16_stepB(cf2* x) {
    const float sg = (float)SGN;
    const float C16[10] = {1.f, 0.92387953f, 0.70710678f, 0.38268343f, 0.f,
                           -0.38268343f, -0.70710678f, -0.92387953f, -1.f, -0.92387953f};
    const float S16[10] = {0.f, 0.38268343f, 0.70710678f, 0.92387953f, 1.f,
                           0.92387953f, 0.70710678f, 0.38268343f, 0.f, -0.38268343f};
    #pragma unroll
    for (int s = 1; s < 4; ++s)
        #pragma unroll
        for (int r = 1; r < 4; ++r) {
            int e = s * r;
            x[4 * s + r] = cmulc(x[4 * s + r], C16[e], sg * S16[e]);
        }
}
template<int SGN>
__device__ __forceinline__ void dft16p(cf2* x) {
    #pragma unroll
    for (int r = 0; r < 4; ++r) dft4p<SGN>(x[r], x[4 + r], x[8 + r], x[12 + r]);
    dft16_stepB<SGN>(x);
    #pragma unroll
    for (int s = 0; s < 4; ++s) dft4p<SGN>(x[4 * s], x[4 * s + 1], x[4 * s + 2], x[4 * s + 3]);
}
template<int SGN>
__device__ __forceinline__ void dft16_halfin(cf2* x) {
    #pragma unroll
    for (int r = 0; r < 4; ++r) dft4p_half<SGN>(x[r], x[4 + r], x[8 + r], x[12 + r]);
    dft16_stepB<SGN>(x);
    #pragma unroll
    for (int s = 0; s < 4; ++s) dft4p<SGN>(x[4 * s], x[4 * s + 1], x[4 * s + 2], x[4 * s + 3]);
}
template<int SGN>
__device__ __forceinline__ void dft16_halfout(cf2* x, cf2* y) {
    #pragma unroll
    for (int r = 0; r < 4; ++r) dft4p<SGN>(x[r], x[4 + r], x[8 + r], x[12 + r]);
    dft16_stepB<SGN>(x);
    #pragma unroll
    for (int s = 0; s < 4; ++s)
        dft4p_out01<SGN>(x[4 * s], x[4 * s + 1], x[4 * s + 2], x[4 * s + 3], y[s], y[4 + s]);
}

// Twiddle powers w^1..w^15 via binary tree: depth 4 (vs 14 serial). Round-7 lesson: table
// loads at per-lane stride 128B are a 64-line gather the compiler won't hoist (VALU 75->43%,
// latency-bound); keep twiddles in the VALU pipe.
template<int SGN>
__device__ __forceinline__ void tw_gen(cf2* w, float p, float invQ) {
    float s1, c1; __sincosf((float)SGN * 6.283185307179586f * p * invQ, &s1, &c1);
    w[1]  = cf2{c1, s1};
    w[2]  = cmul(w[1], w[1]);
    w[3]  = cmul(w[2], w[1]);
    w[4]  = cmul(w[2], w[2]);
    w[5]  = cmul(w[3], w[2]);
    w[6]  = cmul(w[3], w[3]);
    w[7]  = cmul(w[4], w[3]);
    w[8]  = cmul(w[4], w[4]);
    w[9]  = cmul(w[5], w[4]);
    w[10] = cmul(w[5], w[5]);
    w[11] = cmul(w[6], w[5]);
    w[12] = cmul(w[6], w[6]);
    w[13] = cmul(w[7], w[6]);
    w[14] = cmul(w[7], w[7]);
    w[15] = cmul(w[8], w[7]);
}
template<int SGN>
__device__ __forceinline__ void tw_after(cf2* x, float p, float invQ) {
    cf2 w[16];
    tw_gen<SGN>(w, p, invQ);
    #pragma unroll
    for (int m = 1; m < 16; ++m) x[PERM(m)] = cmul(x[PERM(m)], w[m]);
}
template<int SGN>
__device__ __forceinline__ void tw_before(cf2* x, float p, float invQ) {
    cf2 w[16];
    tw_gen<SGN>(w, p, invQ);
    #pragma unroll
    for (int j = 1; j < 16; ++j) x[j] = cmul(x[j], w[j]);
}

// forward: wg<2048 -> packed u-pair rows (uint pair loads); wg>=2048 -> kernel rows (f32, pre-scale 1/4096)
__global__ __launch_bounds__(256) void fft_fwd_kernel(
    const ushort_t* __restrict__ ubf, const float* __restrict__ s4k,
    uint4* __restrict__ uf, uint4* __restrict__ kf)
{
    __shared__ cf2 S[4368];
    int wg = blockIdx.x, t = threadIdx.x;
    cf2 x[16];
    if (wg < 2048) {
        int bp = wg >> 9, e = wg & 511;
        const unsigned int* p0 = (const unsigned int*)ubf + (size_t)e * 8192 + (size_t)bp * 2048;
        #pragma unroll
        for (int j = 0; j < 8; ++j) x[j] = unpack_c(p0[j * 256 + t]);
    } else {
        const float* p0 = s4k + (size_t)(wg - 2048) * 2048;
        #pragma unroll
        for (int j = 0; j < 8; ++j) x[j] = cf2{p0[j * 256 + t], 0.f};
    }
    dft16_halfin<-1>(x);
    tw_after<-1>(x, (float)t, 1.f / 4096.f);
    int tb = 17 * (t >> 4) + (t & 15);
    #pragma unroll
    for (int m = 0; m < 16; ++m) S[tb + 273 * m] = x[PERM(m)];
    __syncthreads();
    int b2 = 273 * (t >> 4) + (t & 15);
    #pragma unroll
    for (int j = 0; j < 16; ++j) x[j] = S[b2 + 17 * j];
    dft16p<-1>(x);
    tw_after<-1>(x, (float)(t & 15), 1.f / 256.f);
    #pragma unroll
    for (int m = 0; m < 16; ++m) S[b2 + 17 * m] = x[PERM(m)];
    __syncthreads();
    int b3 = 273 * (t >> 4) + 17 * (t & 15);
    #pragma unroll
    for (int j = 0; j < 16; ++j) x[j] = S[b3 + j];
    dft16p<-1>(x);
    const float sc = (wg < 2048) ? 1.f : (1.f / 4096.f);
    uint4* dst = ((wg < 2048) ? (uf + (size_t)wg * 1024) : (kf + (size_t)(wg - 2048) * 1024)) + 4 * t;
    #pragma unroll
    for (int q = 0; q < 4; ++q) {
        uint4 o;
        cf2 v0 = x[PERM(4 * q)] * sc, v1 = x[PERM(4 * q + 1)] * sc;
        cf2 v2 = x[PERM(4 * q + 2)] * sc, v3 = x[PERM(4 * q + 3)] * sc;
        o.x = pack_bf2(v0.x, v0.y);
        o.y = pack_bf2(v1.x, v1.y);
        o.z = pack_bf2(v2.x, v2.y);
        o.w = pack_bf2(v3.x, v3.y);
        dst[q] = o;
    }
}

// ============================ fft_inv FUSED with gdt ============================
// spectra product in registers, DIT stages, half-out; then (fused) D-skip + gelu + fragment-major
// store of g directly from registers. XCD-chunked decode: tau = (bid&7)*1024 + bid>>3.
__global__ __launch_bounds__(256) void fft_inv_kernel(
    const uint4* __restrict__ uf, const uint4* __restrict__ kf,
    const unsigned int* __restrict__ ub2, const float* __restrict__ s4D,
    ushort_t* __restrict__ gT)
{
    __shared__ cf2 S[4368];
    int bid = blockIdx.x, t = threadIdx.x;
    int tau = (bid & 7) * 1024 + (bid >> 3);      // bijective, 8192 % 8 == 0
    int e = tau >> 4, ch = (tau >> 2) & 3, bp = tau & 3;
    int r = ch * 512 + e;
    const uint4* zr = uf + (size_t)(bp * 512 + e) * 1024 + 4 * t;
    const uint4* kr = kf + (size_t)(ch * 512 + e) * 1024 + 4 * t;
    cf2 x[16];
    #pragma unroll
    for (int q = 0; q < 4; ++q) {
        uint4 a4 = zr[q], b4 = kr[q];
        x[4 * q + 0] = cmul(unpack_c(a4.x), unpack_c(b4.x));
        x[4 * q + 1] = cmul(unpack_c(a4.y), unpack_c(b4.y));
        x[4 * q + 2] = cmul(unpack_c(a4.z), unpack_c(b4.z));
        x[4 * q + 3] = cmul(unpack_c(a4.w), unpack_c(b4.w));
    }
    dft16p<1>(x);
    int b1 = 273 * (t >> 4) + 17 * (t & 15);
    #pragma unroll
    for (int m = 0; m < 16; ++m) S[b1 + m] = x[PERM(m)];
    __syncthreads();
    int b2 = 273 * (t >> 4) + (t & 15);
    #pragma unroll
    for (int j = 0; j < 16; ++j) x[j] = S[b2 + 17 * j];
    tw_before<1>(x, (float)(t & 15), 1.f / 256.f);
    dft16p<1>(x);
    #pragma unroll
    for (int m = 0; m < 16; ++m) S[b2 + 17 * m] = x[PERM(m)];
    __syncthreads();
    int b3 = 17 * (t >> 4) + (t & 15);
    #pragma unroll
    for (int j = 0; j < 16; ++j) x[j] = S[b3 + 273 * j];
    tw_before<1>(x, (float)t, 1.f / 4096.f);
    cf2 y[8];
    dft16_halfout<1>(x, y);

    // ---- fused gdt: y + D*u, gelu, fragment-major store (same index formula as old gdt) ----
    const float d = s4D[r];
    const unsigned int* ur = ub2 + (size_t)e * 8192 + (size_t)bp * 2048 + t;
    const size_t rpart = (size_t)(r >> 5) * 524288 + (size_t)(((r >> 3) & 3) * 128 + (r & 7));
    #pragma unroll
    for (int m = 0; m < 8; ++m) {
        int l = m * 256 + t;
        cf2 u2 = unpack_c(ur[m * 256]);
        float v0 = gelu_f(fmaf(d, u2.x, y[m].x));
        float v1 = gelu_f(fmaf(d, u2.y, y[m].y));
        int n_lo = bp * 4096 + l;                 // batch 2bp at position l; n_hi = n_lo + 2048
        size_t npart = (size_t)(n_lo >> 6) * 2048 + (size_t)(((n_lo >> 4) & 3) * 512 + (n_lo & 15) * 8);
        gT[rpart + npart]         = f2bfu(v0);
        gT[rpart + npart + 65536] = f2bfu(v1);    // +2048 in n -> +32*2048 ushorts
    }
}

// ============================ gemmF: EPI5 fragment-direct GEMM — no LDS, no barriers in K-loop ============
// Operands pre-stored fragment-major (Acomb via EPI2 epilogue, g via fused fft_inv): each lane loads its
// MFMA fragment as one coalesced global_load_dwordx4 from L2/L3. Depth-2 register pipeline.
__global__ __launch_bounds__(256) void gemmF_kernel(
    const ushort_t* __restrict__ Af, const ushort_t* __restrict__ Bf,
    ushort_t* __restrict__ Cb, const float* __restrict__ bias)
{
    __shared__ ushort_t SM[8704];                    // epilogue gate tile [128][68] only
    const int t = threadIdx.x;
    const int w = t >> 6, lane = t & 63, quad = lane >> 4, lr = lane & 15;
    const int wm = (w >> 1) * 64;
    const int by = blockIdx.y, n0 = blockIdx.x * 128;
    const int h = (w >> 1) ? (4 + by) : by;          // A row-block: rows {64by..} / {256+64by..}
    const int nb = (n0 >> 6) + (w & 1);              // B col-block of 64

    const ushort_t* Aw = Af + (size_t)h * 2048 + (size_t)lane * 8;   // + s*16384 + im*512
    const ushort_t* Bw = Bf + (size_t)nb * 2048 + (size_t)lane * 8;  // + s*524288 + in*512

    float4_t acc[4][4];
    #pragma unroll
    for (int i = 0; i < 4; ++i)
        #pragma unroll
        for (int j = 0; j < 4; ++j) { float4_t z = {0.f, 0.f, 0.f, 0.f}; acc[i][j] = z; }

    short8 a0[4], a1[4], b0[4], b1[4];

#define LDA(D, S) do { _Pragma("unroll") for (int i_ = 0; i_ < 4; ++i_) \
        D[i_] = *(const short8*)(Aw + (size_t)(S) * 16384 + i_ * 512); } while (0)
#define LDB(D, S) do { _Pragma("unroll") for (int i_ = 0; i_ < 4; ++i_) \
        D[i_] = *(const short8*)(Bw + (size_t)(S) * 524288 + i_ * 512); } while (0)
#define CMP(AA, BB) do { _Pragma("unroll") for (int im_ = 0; im_ < 4; ++im_) \
        _Pragma("unroll") for (int in_ = 0; in_ < 4; ++in_) \
            acc[im_][in_] = __builtin_amdgcn_mfma_f32_16x16x32_bf16(AA[im_], BB[in_], acc[im_][in_], 0, 0, 0); } while (0)

    LDA(a0, 0); LDB(b0, 0);
    LDA(a1, 1); LDB(b1, 1);
    for (int s = 0; s < 64; s += 2) {                // K = 2048 fixed -> 64 steps of 32
        CMP(a0, b0);
        if (s + 2 < 64) { LDA(a0, s + 2); LDB(b0, s + 2); }
        CMP(a1, b1);
        if (s + 3 < 64) { LDA(a1, s + 3); LDB(b1, s + 3); }
    }
#undef LDA
#undef LDB
#undef CMP

    // ---- gate-fused epilogue (identical math to previous EPI5) ----
    #pragma unroll
    for (int p = 0; p < 2; ++p) {
        if (p) __syncthreads();
        if ((w & 1) == p) {                          // waves owning this n-half
            #pragma unroll
            for (int im = 0; im < 4; ++im)
                #pragma unroll
                for (int in_ = 0; in_ < 4; ++in_) {
                    int nl = in_ * 16 + lr;
                    #pragma unroll
                    for (int r = 0; r < 4; ++r) {
                        int i = wm + im * 16 + quad * 4 + r;
                        int me = (i < 64) ? (64 * by + i) : (192 + 64 * by + i);
                        SM[i * 68 + nl] = f2bfu(acc[im][in_][r] + bias[me]);
                    }
                }
        }
        __syncthreads();
        int nl = t >> 2, gcb = (t & 3) * 16;
        size_t obase = (size_t)(n0 + 64 * p + nl) * 256 + 64 * by + gcb;
        short8 o0, o1;
        #pragma unroll
        for (int j = 0; j < 16; ++j) {
            int gc = gcb + j;
            float a = bf2f(SM[gc * 68 + nl]);
            float bb = bf2f(SM[(gc + 64) * 68 + nl]);
            ushort_t gv = f2bfu(tanh_f(a) * sigmoid_f(bb));
            if (j < 8) o0[j] = (short)gv; else o1[j - 8] = (short)gv;
        }
        *(short8*)(Cb + obase) = o0;
        *(short8*)(Cb + obase + 8) = o1;
    }
}

// ============================ gemm: 128Mx64N tile, global_load_lds, static dbuf (round-3) ============================
// Used for the short-K gemms (conv K=768, EPI4 K=256, prep K=512). EPI2 writes its output
// (Acomb) in A-FRAGMENT-major layout for gemmF.
template<int BSRC, int EPI>
__global__ __launch_bounds__(256, 4) void gemm_kernel(
    const ushort_t* __restrict__ A, const ushort_t* __restrict__ Bm,
    ushort_t* __restrict__ Cb, float* __restrict__ Cf,
    int M, int N, int K,
    const float* __restrict__ bias, const float* __restrict__ bias2,
    const ushort_t* __restrict__ xnb, float* __restrict__ dout)
{
    __shared__ ushort_t SM[16384];       // 2 x 8192 (32 KB)
    const int t = threadIdx.x;
    const int n0 = blockIdx.x * 64, m0 = blockIdx.y * 128;
    const int w = t >> 6, lane = t & 63, quad = lane >> 4, lr = lane & 15;
    const int wm = (w >> 1) * 64, wn = (w & 1) * 32;

    // ---- staging geometry ----
    const int srow = lane >> 2;                              // row within 16-row issue group
    const int swslot = ((lane & 3) ^ ((lane >> 3) & 3)) * 8; // pre-swizzled col slot (ushorts)
    const int r0q = w * 32 + srow;                           // A q=0 tile-row; q=1 adds 16
    int ar0 = m0 + r0q, ar1 = m0 + r0q + 16;
    const ushort_t* aSrc0 = A + (size_t)ar0 * K + swslot;
    const ushort_t* aSrc1 = A + (size_t)ar1 * K + swslot;
    const int nrow = n0 + w * 16 + srow;                     // B tile-row (one issue/wave)
    const ushort_t* bSrc;
    if (BSRC == 0) bSrc = Bm + (size_t)nrow * K + swslot;
    else           bSrc = Bm + (size_t)((nrow >> 11) * 2050 + (nrow & 2047)) * 256 + swslot;

    // wave-uniform LDS dest offsets within a buffer (ushort units; lane*16B added by HW)
    const int aD = w * 1024;             // A region [0,4096)
    const int bD = 4096 + w * 512;       // B region [4096,6144)

    float4_t acc[4][2];
    #pragma unroll
    for (int i = 0; i < 4; ++i)
        #pragma unroll
        for (int j = 0; j < 2; ++j) { float4_t z = {0.f, 0.f, 0.f, 0.f}; acc[i][j] = z; }

    const int qsw = (quad ^ ((lr >> 1) & 3)) << 3;           // read-side swizzled slot (ushorts)

#define STAGE(BUF, KK) do {                                                     \
        cp16(aSrc0 + (KK), SM + (BUF) + aD);                                    \
        cp16(aSrc1 + (KK), SM + (BUF) + aD + 512);                              \
        if (BSRC == 0) cp16(bSrc + (KK), SM + (BUF) + bD);                      \
        else cp16(bSrc + (((KK) >> 8) * 256 + ((KK) & 255)), SM + (BUF) + bD);  \
    } while (0)

#define COMPUTE(BUF) do {                                                       \
        const ushort_t* Al = SM + (BUF);                                        \
        const ushort_t* Bl = SM + (BUF) + 4096;                                 \
        short8 af[4], bfr[2];                                                   \
        _Pragma("unroll")                                                       \
        for (int im = 0; im < 4; ++im)                                          \
            af[im] = *(const short8*)&Al[(wm + im * 16 + lr) * 32 + qsw];       \
        _Pragma("unroll")                                                       \
        for (int in_ = 0; in_ < 2; ++in_)                                       \
            bfr[in_] = *(const short8*)&Bl[(wn + in_ * 16 + lr) * 32 + qsw];    \
        _Pragma("unroll")                                                       \
        for (int im = 0; im < 4; ++im)                                          \
            _Pragma("unroll")                                                   \
            for (int in_ = 0; in_ < 2; ++in_)                                   \
                acc[im][in_] = __builtin_amdgcn_mfma_f32_16x16x32_bf16(         \
                    af[im], bfr[in_], acc[im][in_], 0, 0, 0);                   \
    } while (0)

    // prologue: stage K-tile 0 into buffer 0
    STAGE(0, 0);
    __syncthreads();                             // drains vmcnt(0): tile 0 ready

    for (int kt = 0; kt < K; kt += 64) {         // K % 64 == 0 for all instantiations
        STAGE(8192, kt + 32);                    // prefetch odd tile into buf1
        COMPUTE(0);
        __syncthreads();                         // buf1 ready; buf0 reads done
        if (kt + 64 < K) STAGE(0, kt + 64);      // prefetch next even tile into buf0
        COMPUTE(8192);
        __syncthreads();                         // buf0 ready; buf1 reads done
    }
#undef STAGE
#undef COMPUTE

    #pragma unroll
    for (int im = 0; im < 4; ++im) {
        #pragma unroll
        for (int in_ = 0; in_ < 2; ++in_) {
            int n = n0 + wn + in_ * 16 + lr;
            int mb = m0 + wm + im * 16 + quad * 4;
            #pragma unroll
            for (int r = 0; r < 4; ++r) {
                int m = mb + r;
                float v = acc[im][in_][r];
                if (EPI == 0) {
                    v += bias[m];
                    ((__hip_bfloat16*)Cb)[(size_t)m * N + n] = __float2bfloat16(gelu_f(v));
                } else if (EPI == 1) {
                    v += (m == n) ? 1.0f : 0.0f;
                    ((__hip_bfloat16*)Cb)[(size_t)m * N + n] = __float2bfloat16(v);
                } else if (EPI == 2) {
                    // A-fragment-major write for gemmF:
                    // idx16 = ((s*8 + h)*4 + im)*64 + quad*16 + lr ; ushort = idx16*8 + j
                    size_t fi = ((((size_t)(n >> 5) * 8 + (m >> 6)) * 4 + ((m >> 4) & 3)) * 64
                                 + ((n >> 3) & 3) * 16 + (m & 15)) * 8 + (n & 7);
                    Cb[fi] = f2bfu(v);
                } else {
                    int bb = n >> 11, ll = n & 2047;
                    if (m < 256) {
                        v += bias[m];
                        int idx = (bb << 19) + (m << 11) + ll;
                        dout[idx] = (bf2f(xnb[idx]) + v) * 0.70710678118654752f;
                    } else {
                        v += bias2[m - 256];
                        dout[4194304 + (bb << 19) + ((m - 256) << 11) + ll] = v;
                    }
                }
            }
        }
    }
}

// ============================ launch ============================
extern "C" void kernel_launch(void* const* d_in, const int* in_sizes, int n_in,
                              void* d_out, int out_size, void* d_ws, size_t ws_size,
                              hipStream_t stream)
{
    const float* x         = (const float*)d_in[0];
    const float* original  = (const float*)d_in[1];
    const float* sn_scale  = (const float*)d_in[2];
    const float* conv_w    = (const float*)d_in[3];
    const float* conv_b    = (const float*)d_in[4];
    const float* s4_ln_g   = (const float*)d_in[5];
    const float* s4_ln_b   = (const float*)d_in[6];
    const float* s4_kernel = (const float*)d_in[7];
    const float* s4_D      = (const float*)d_in[8];
    const float* s4_out_w  = (const float*)d_in[9];
    const float* s4_out_b  = (const float*)d_in[10];
    const float* attn_v_w  = (const float*)d_in[11];
    const float* attn_v_b  = (const float*)d_in[12];
    const float* attn_o_w  = (const float*)d_in[13];
    const float* attn_o_b  = (const float*)d_in[14];
    const float* res_w     = (const float*)d_in[15];
    const float* res_b     = (const float*)d_in[16];
    const float* skip_w    = (const float*)d_in[17];
    const float* skip_b    = (const float*)d_in[18];

    char* ws = (char*)d_ws;
    __hip_bfloat16* convA = (__hip_bfloat16*)(ws + WS_CONVA);
    __hip_bfloat16* WvT   = (__hip_bfloat16*)(ws + WS_WV);
    __hip_bfloat16* WoBf  = (__hip_bfloat16*)(ws + WS_WO);
    __hip_bfloat16* W1T   = (__hip_bfloat16*)(ws + WS_W1);
    __hip_bfloat16* Wcat  = (__hip_bfloat16*)(ws + WS_WCAT);
    ushort_t* A2    = (ushort_t*)(ws + WS_A2);
    ushort_t* Acomb = (ushort_t*)(ws + WS_ACOMB);
    float* bcombp  = (float*)(ws + WS_BCOMB);
    ushort_t* xnb  = (ushort_t*)(ws + WS_XN);
    ushort_t* h0pT = (ushort_t*)(ws + WS_H0PT);
    ushort_t* hP   = (ushort_t*)(ws + WS_U);
    ushort_t* ubP  = (ushort_t*)(ws + WS_UB);
    uint4* ufP = (uint4*)(ws + WS_UF);
    uint4* kfP = (uint4*)(ws + WS_KF);
    ushort_t* gT    = (ushort_t*)(ws + WS_GTF);
    ushort_t* gateT = (ushort_t*)(ws + WS_GATET);

    // weight prep + attention-fold precompute
    wprep_kernel<<<dim3(4096), dim3(256), 0, stream>>>(conv_w, attn_v_w, attn_o_w, s4_out_w,
        res_w, skip_w, convA, WvT, WoBf, W1T, Wcat);
    gemm_kernel<0, 1><<<dim3(8, 4), dim3(256), 0, stream>>>(
        (const ushort_t*)WoBf, (const ushort_t*)WvT, A2, nullptr, 512, 512, 512,
        nullptr, nullptr, nullptr, nullptr);
    bias2_kernel<<<dim3(512), dim3(256), 0, stream>>>(
        (const __hip_bfloat16*)A2, s4_out_b, attn_o_w, attn_v_b, attn_o_b, bcombp);
    gemm_kernel<0, 2><<<dim3(32, 4), dim3(256), 0, stream>>>(
        A2, (const ushort_t*)W1T, Acomb, nullptr, 512, 2048, 512,
        nullptr, nullptr, nullptr, nullptr);

    // main pipeline
    prep_kernel<<<dim3(256), dim3(512), 0, stream>>>(x, original, sn_scale, xnb, h0pT);
    gemm_kernel<1, 0><<<dim3(256, 4), dim3(256), 0, stream>>>(
        (const ushort_t*)convA, h0pT, hP, nullptr, 512, NBL, 768,
        conv_b, nullptr, nullptr, nullptr);
    ln_kernel<<<dim3(256), dim3(512), 0, stream>>>(hP, ubP, s4_ln_g, s4_ln_b);
    fft_fwd_kernel<<<dim3(4096), dim3(256), 0, stream>>>(ubP, s4_kernel, ufP, kfP);
    fft_inv_kernel<<<dim3(8192), dim3(256), 0, stream>>>(
        ufP, kfP, (const unsigned int*)ubP, s4_D, gT);
    gemmF_kernel<<<dim3(128, 4), dim3(256), 0, stream>>>(
        (const ushort_t*)Acomb, gT, gateT, bcombp);
    gemm_kernel<0, 4><<<dim3(256, 4), dim3(256), 0, stream>>>(
        (const ushort_t*)Wcat, gateT, nullptr, nullptr, 512, NBL, 256,
        res_b, skip_b, xnb, (float*)d_out);
}

// Round 9
// 377.369 us; speedup vs baseline: 1.1693x; 1.0232x over previous
//
#include <hip/hip_runtime.h>
#include <hip/hip_bf16.h>
#include <math.h>

typedef __attribute__((ext_vector_type(8))) short short8;
typedef __attribute__((ext_vector_type(4))) float float4_t;
typedef __attribute__((ext_vector_type(2))) float cf2;   // complex (re, im) -> v_pk_* ops
typedef unsigned short ushort_t;
typedef unsigned int uint_t;

// Problem constants: B=8, C=256, L=2048, E=512, CH=4
#define NBL 16384          // B*L

// ---------------- workspace layout (bytes) ----------------
#define WS_CONVA   ((size_t)0)          // bf16 [512][768]  K reordered: k' = dk*256 + c
#define WS_WV      ((size_t)786432)     // bf16 [512][512]  Wv^T
#define WS_WO      ((size_t)1310720)    // bf16 [512][512]  Wo natural
#define WS_W1      ((size_t)1835008)    // bf16 [2048][512] s4_out_w^T
#define WS_WCAT    ((size_t)3932160)    // bf16 [512][256]
#define WS_A2      ((size_t)4194304)    // bf16 [512][512]  I + Wo@Wv
#define WS_ACOMB   ((size_t)4718592)    // bf16 FRAGMENT-major [s=k/32][h=m/64][im][lane][j] (2 MB)
#define WS_BCOMB   ((size_t)6815744)    // f32 [512]
#define WS_XN      ((size_t)6819840)    // bf16 [8][256][2048]
#define WS_H0PT    ((size_t)23597056)   // bf16 [16400][256]  padded x+orig, transposed
#define WS_U       ((size_t)31993856)   // bf16 [512][16384]  conv+gelu output h
#define WS_UF      ((size_t)65548288)   // bf162 [2048][4096] u-pair spectra (32 MB, ends 99102720)
#define WS_KF      ((size_t)99102720)   // bf162 [2048][4096] kernel spectra (pre-scaled 1/4096)
#define WS_GTF     ((size_t)132657152)  // bf16 FRAGMENT-major g [s][nb][in][lane][j] (64 MB, ends 199766016)
#define WS_GATET   ((size_t)199766016)  // bf16 [16384][256]  (ends 208154624)
#define WS_UB      ((size_t)208162816)  // bf16-pair uint [512][8192]  LN output u, end 224940032

// ---------------- fast transcendental helpers ----------------
__device__ __forceinline__ float gelu_f(float x) {
    float t = x * x;
    float a2 = x * fmaf(0.07135481627f, t, 1.59576912161f);
    return x / (1.f + __expf(-a2));
}
__device__ __forceinline__ float tanh_f(float a) {
    return 1.f - 2.f / (1.f + __expf(2.f * a));
}
__device__ __forceinline__ float sigmoid_f(float b) {
    return 1.f / (1.f + __expf(-b));
}

__device__ __forceinline__ unsigned int pack_bf2(float a, float b) {
#if __has_builtin(__builtin_amdgcn_cvt_pk_bf16_f32)
    auto v = __builtin_amdgcn_cvt_pk_bf16_f32(a, b);
    unsigned int r; __builtin_memcpy(&r, &v, 4); return r;
#else
    __hip_bfloat16 ha = __float2bfloat16(a), hb = __float2bfloat16(b);
    unsigned short ua = *(unsigned short*)&ha, ub = *(unsigned short*)&hb;
    return (unsigned int)ua | ((unsigned int)ub << 16);
#endif
}
__device__ __forceinline__ ushort_t f2bfu(float a) {
    __hip_bfloat16 h = __float2bfloat16(a);
    return *(ushort_t*)&h;
}
__device__ __forceinline__ cf2 unpack_c(unsigned int v) {
    cf2 r;
    r.x = __uint_as_float(v << 16);
    r.y = __uint_as_float(v & 0xffff0000u);
    return r;
}
__device__ __forceinline__ float bf2f(ushort_t u) {
    return __uint_as_float(((unsigned int)u) << 16);
}

// async global->LDS 16B per lane. LDS dest is WAVE-UNIFORM base + lane*16 (m104);
// global src is per-lane.
__device__ __forceinline__ void cp16(const ushort_t* g, ushort_t* l) {
    __builtin_amdgcn_global_load_lds(
        (__attribute__((address_space(1))) void*)(void*)g,
        (__attribute__((address_space(3))) void*)l, 16, 0, 0);
}

// ---------------- packed complex primitives ----------------
__device__ __forceinline__ cf2 cswap(cf2 a) { return __builtin_shufflevector(a, a, 1, 0); }
template<int SGN>
__device__ __forceinline__ cf2 cmuli(cf2 a) {
    cf2 s = cswap(a);
    return s * cf2{(float)(-SGN), (float)SGN};
}
__device__ __forceinline__ cf2 cmul(cf2 a, cf2 b) {
    cf2 t = cswap(a) * cf2{-b.y, b.y};
    return a * cf2{b.x, b.x} + t;
}
__device__ __forceinline__ cf2 cmulc(cf2 a, float wr, float wi) {
    cf2 t = cswap(a) * cf2{-wi, wi};
    return a * cf2{wr, wr} + t;
}

// ============================ weight prep ============================
__global__ __launch_bounds__(256) void wprep_kernel(
    const float* __restrict__ conv_w, const float* __restrict__ attn_v_w,
    const float* __restrict__ attn_o_w, const float* __restrict__ s4_out_w,
    const float* __restrict__ res_w, const float* __restrict__ skip_w,
    __hip_bfloat16* __restrict__ convA, __hip_bfloat16* __restrict__ WvT,
    __hip_bfloat16* __restrict__ WoBf, __hip_bfloat16* __restrict__ W1T,
    __hip_bfloat16* __restrict__ Wcat)
{
    const int N0 = 393216, N1 = 655360, N2c = 917504, N3 = 1966080, N4 = 2097152;
    for (int i = blockIdx.x * 256 + threadIdx.x; i < N4; i += gridDim.x * 256) {
        if (i < N0) {
            int m = i / 768, r = i - m * 768, dk = r >> 8, c = r & 255;
            convA[i] = __float2bfloat16(conv_w[m * 768 + c * 3 + dk]);
        } else if (i < N1) {
            int j = i - N0; int row = j >> 9, e = j & 511;
            WvT[j] = __float2bfloat16(attn_v_w[e * 512 + row]);
        } else if (i < N2c) {
            WoBf[i - N1] = __float2bfloat16(attn_o_w[i - N1]);
        } else if (i < N3) {
            int j = i - N2c; int ck = j >> 9, e = j & 511;
            W1T[j] = __float2bfloat16(s4_out_w[e * 2048 + ck]);
        } else {
            int j = i - N3; int m = j >> 8, c = j & 255;
            float v = (m < 256) ? res_w[m * 256 + c] : skip_w[(m - 256) * 256 + c];
            Wcat[j] = __float2bfloat16(v);
        }
    }
}

__global__ __launch_bounds__(256) void bias2_kernel(
    const __hip_bfloat16* __restrict__ A2, const float* __restrict__ s4_out_b,
    const float* __restrict__ attn_o_w, const float* __restrict__ attn_v_b,
    const float* __restrict__ attn_o_b, float* __restrict__ bcomb)
{
    __shared__ float red[256];
    int o = blockIdx.x, t = threadIdx.x;
    float s = 0.f;
    for (int e = t; e < 512; e += 256)
        s += __bfloat162float(A2[o * 512 + e]) * s4_out_b[e] + attn_o_w[o * 512 + e] * attn_v_b[e];
    red[t] = s; __syncthreads();
    for (int k = 128; k > 0; k >>= 1) { if (t < k) red[t] += red[t + k]; __syncthreads(); }
    if (t == 0) bcomb[o] = red[0] + attn_o_b[o];
}

// ============================ prep: RMSNorm->xn bf16, (x+orig)->h0pT via LDS tile ============================
__global__ __launch_bounds__(512) void prep_kernel(
    const float* __restrict__ x, const float* __restrict__ orig,
    const float* __restrict__ sn, ushort_t* __restrict__ xnb, ushort_t* __restrict__ h0pT)
{
    __shared__ float red[8][64];
    __shared__ ushort_t T[256 * 66];
    int blk = blockIdx.x, t = threadIdx.x;
    int lane = t & 63, cg = t >> 6;
    int b = blk >> 5, l0 = (blk & 31) << 6;
    size_t basein = (size_t)b * 524288 + l0 + lane;
    float ss = 0.f;
    for (int c = cg; c < 256; c += 8) {
        size_t idx = basein + (size_t)c * 2048;
        float xv = x[idx], ov = orig[idx];
        ss += xv * xv;
        T[c * 66 + lane] = f2bfu(xv + ov);
    }
    red[cg][lane] = ss;
    __syncthreads();
    float tot = 0.f;
    #pragma unroll
    for (int k = 0; k < 8; ++k) tot += red[k][lane];
    float inv = 1.0f / (sqrtf(tot) * 0.0625f + 1e-8f);
    __hip_bfloat16* xo = (__hip_bfloat16*)xnb;
    for (int c = cg; c < 256; c += 8) {
        size_t idx = basein + (size_t)c * 2048;
        xo[idx] = __float2bfloat16(sn[c] * x[idx] * inv);
    }
    int c2 = t & 255, half = t >> 8;
    size_t rowbase = (size_t)(b * 2050 + 1 + l0);
    for (int r = half; r < 64; r += 2)
        h0pT[(rowbase + r) * 256 + c2] = T[c2 * 66 + r];
    if ((blk & 31) == 0) {
        if (t < 256) h0pT[(size_t)(b * 2050) * 256 + t] = 0;
        else         h0pT[(size_t)(b * 2050 + 2049) * 256 + (t - 256)] = 0;
    }
}

// ============================ LayerNorm over E: bf16 h -> pair-interleaved bf16 u ============================
// u stored as uint pairs: ushort idx = e*16384 + (b>>1)*4096 + 2*l + (b&1)
__global__ __launch_bounds__(512) void ln_kernel(
    const ushort_t* __restrict__ h, ushort_t* __restrict__ ub,
    const float* __restrict__ gam, const float* __restrict__ bet)
{
    __shared__ float r1[8][64], r2[8][64];
    int blk = blockIdx.x, t = threadIdx.x;
    int lane = t & 63, og = t >> 6;
    int n = (blk << 6) + lane;
    float s1 = 0.f, s2 = 0.f;
    for (int o = og; o < 512; o += 8) { float v = bf2f(h[(size_t)o * NBL + n]); s1 += v; s2 += v * v; }
    r1[og][lane] = s1; r2[og][lane] = s2;
    __syncthreads();
    float mu = 0.f, m2 = 0.f;
    #pragma unroll
    for (int k = 0; k < 8; ++k) { mu += r1[k][lane]; m2 += r2[k][lane]; }
    mu *= (1.f / 512.f); m2 *= (1.f / 512.f);
    float rstd = rsqrtf(m2 - mu * mu + 1e-5f);
    int b = n >> 11, l = n & 2047;
    size_t sbase = (size_t)(b >> 1) * 4096 + 2 * l + (b & 1);
    for (int o = og; o < 512; o += 8) {
        size_t idx = (size_t)o * NBL + n;
        ub[(size_t)o * 16384 + sbase] = f2bfu((bf2f(h[idx]) - mu) * rstd * gam[o] + bet[o]);
    }
}

// ============================ FFT: 4096-pt radix-16 ============================
// LDS: logical element (B,c,d) in 16^3 stored at phys = 256*B + 16*c + (c^d).
// Exactly 4096 cf2 = 32 KB -> 5 blocks/CU (vs 35,328 B padded -> 4). The 4-bit XOR swizzle
// is conflict-free (minimum-wrap) for all 8 access patterns of both kernels: any pattern
// varies exactly one of {B, c, d} per 16-lane group, and c^d spreads the stride-16 case
// (c per-lane, d fixed) across all 32 banks. Applied identically at every read AND write
// (rule #21). Arithmetic unchanged -> bit-identical output.
#define PERM(m) ((((m) & 3) << 2) | ((m) >> 2))

template<int SGN>
__device__ __forceinline__ void dft4p(cf2& a0, cf2& a1, cf2& a2, cf2& a3) {
    cf2 t0 = a0 + a2, t1 = a0 - a2, t2 = a1 + a3, t3 = a1 - a3;
    cf2 j3 = cmuli<SGN>(t3);
    a0 = t0 + t2; a2 = t0 - t2;
    a1 = t1 + j3; a3 = t1 - j3;
}
template<int SGN>
__device__ __forceinline__ void dft4p_half(cf2& a0, cf2& a1, cf2& a2, cf2& a3) {
    cf2 u0 = a0, u1 = a1;
    cf2 j1 = cmuli<SGN>(u1);
    a0 = u0 + u1; a2 = u0 - u1;
    a1 = u0 + j1; a3 = u0 - j1;
}
template<int SGN>
__device__ __forceinline__ void dft4p_out01(cf2 a0, cf2 a1, cf2 a2, cf2 a3, cf2& o0, cf2& o1) {
    cf2 t0 = a0 + a2, t1 = a0 - a2, t2 = a1 + a3, t3 = a1 - a3;
    o0 = t0 + t2;
    o1 = t1 + cmuli<SGN>(t3);
}

template<int SGN>
__device__ __forceinline__ void dft16_stepB(cf2* x) {
    const float sg = (float)SGN;
    const float C16[10] = {1.f, 0.92387953f, 0.70710678f, 0.38268343f, 0.f,
                           -0.38268343f, -0.70710678f, -0.92387953f, -1.f, -0.92387953f};
    const float S16[10] = {0.f, 0.38268343f, 0.70710678f, 0.92387953f, 1.f,
                           0.92387953f, 0.70710678f, 0.38268343f, 0.f, -0.38268343f};
    #pragma unroll
    for (int s = 1; s < 4; ++s)
        #pragma unroll
        for (int r = 1; r < 4; ++r) {
            int e = s * r;
            x[4 * s + r] = cmulc(x[4 * s + r], C16[e], sg * S16[e]);
        }
}
template<int SGN>
__device__ __forceinline__ void dft16p(cf2* x) {
    #pragma unroll
    for (int r = 0; r < 4; ++r) dft4p<SGN>(x[r], x[4 + r], x[8 + r], x[12 + r]);
    dft16_stepB<SGN>(x);
    #pragma unroll
    for (int s = 0; s < 4; ++s) dft4p<SGN>(x[4 * s], x[4 * s + 1], x[4 * s + 2], x[4 * s + 3]);
}
template<int SGN>
__device__ __forceinline__ void dft16_halfin(cf2* x) {
    #pragma unroll
    for (int r = 0; r < 4; ++r) dft4p_half<SGN>(x[r], x[4 + r], x[8 + r], x[12 + r]);
    dft16_stepB<SGN>(x);
    #pragma unroll
    for (int s = 0; s < 4; ++s) dft4p<SGN>(x[4 * s], x[4 * s + 1], x[4 * s + 2], x[4 * s + 3]);
}
template<int SGN>
__device__ __forceinline__ void dft16_halfout(cf2* x, cf2* y) {
    #pragma unroll
    for (int r = 0; r < 4; ++r) dft4p<SGN>(x[r], x[4 + r], x[8 + r], x[12 + r]);
    dft16_stepB<SGN>(x);
    #pragma unroll
    for (int s = 0; s < 4; ++s)
        dft4p_out01<SGN>(x[4 * s], x[4 * s + 1], x[4 * s + 2], x[4 * s + 3], y[s], y[4 + s]);
}

// Twiddle powers w^1..w^15 via binary tree: depth 4 (vs 14 serial). Round-7 lesson: table
// loads at per-lane stride 128B are a 64-line gather the compiler won't hoist (VALU 75->43%,
// latency-bound); keep twiddles in the VALU pipe.
template<int SGN>
__device__ __forceinline__ void tw_gen(cf2* w, float p, float invQ) {
    float s1, c1; __sincosf((float)SGN * 6.283185307179586f * p * invQ, &s1, &c1);
    w[1]  = cf2{c1, s1};
    w[2]  = cmul(w[1], w[1]);
    w[3]  = cmul(w[2], w[1]);
    w[4]  = cmul(w[2], w[2]);
    w[5]  = cmul(w[3], w[2]);
    w[6]  = cmul(w[3], w[3]);
    w[7]  = cmul(w[4], w[3]);
    w[8]  = cmul(w[4], w[4]);
    w[9]  = cmul(w[5], w[4]);
    w[10] = cmul(w[5], w[5]);
    w[11] = cmul(w[6], w[5]);
    w[12] = cmul(w[6], w[6]);
    w[13] = cmul(w[7], w[6]);
    w[14] = cmul(w[7], w[7]);
    w[15] = cmul(w[8], w[7]);
}
template<int SGN>
__device__ __forceinline__ void tw_after(cf2* x, float p, float invQ) {
    cf2 w[16];
    tw_gen<SGN>(w, p, invQ);
    #pragma unroll
    for (int m = 1; m < 16; ++m) x[PERM(m)] = cmul(x[PERM(m)], w[m]);
}
template<int SGN>
__device__ __forceinline__ void tw_before(cf2* x, float p, float invQ) {
    cf2 w[16];
    tw_gen<SGN>(w, p, invQ);
    #pragma unroll
    for (int j = 1; j < 16; ++j) x[j] = cmul(x[j], w[j]);
}

// forward: wg<2048 -> packed u-pair rows (uint pair loads); wg>=2048 -> kernel rows (f32, pre-scale 1/4096)
__global__ __launch_bounds__(256, 5) void fft_fwd_kernel(
    const ushort_t* __restrict__ ubf, const float* __restrict__ s4k,
    uint4* __restrict__ uf, uint4* __restrict__ kf)
{
    __shared__ cf2 S[4096];                     // exactly 32 KB -> 5 blocks/CU
    int wg = blockIdx.x, t = threadIdx.x;
    int tc = t >> 4, td = t & 15;
    int base = tc << 8;                         // 256*tc
    cf2 x[16];
    if (wg < 2048) {
        int bp = wg >> 9, e = wg & 511;
        const unsigned int* p0 = (const unsigned int*)ubf + (size_t)e * 8192 + (size_t)bp * 2048;
        #pragma unroll
        for (int j = 0; j < 8; ++j) x[j] = unpack_c(p0[j * 256 + t]);
    } else {
        const float* p0 = s4k + (size_t)(wg - 2048) * 2048;
        #pragma unroll
        for (int j = 0; j < 8; ++j) x[j] = cf2{p0[j * 256 + t], 0.f};
    }
    dft16_halfin<-1>(x);
    tw_after<-1>(x, (float)t, 1.f / 4096.f);
    // store1: (B=m, c=tc, d=td) -> 256m + 16tc + (tc^td)
    int s1 = (tc << 4) + (tc ^ td);
    #pragma unroll
    for (int m = 0; m < 16; ++m) S[(m << 8) + s1] = x[PERM(m)];
    __syncthreads();
    // read1: (B=tc, c=j, d=td)
    #pragma unroll
    for (int j = 0; j < 16; ++j) x[j] = S[base + (j << 4) + (j ^ td)];
    dft16p<-1>(x);
    tw_after<-1>(x, (float)td, 1.f / 256.f);
    // store2: (B=tc, c=m, d=td)
    #pragma unroll
    for (int m = 0; m < 16; ++m) S[base + (m << 4) + (m ^ td)] = x[PERM(m)];
    __syncthreads();
    // read2: (B=tc, c=td, d=j)
    int b2r = base + (td << 4);
    #pragma unroll
    for (int j = 0; j < 16; ++j) x[j] = S[b2r + (td ^ j)];
    dft16p<-1>(x);
    const float sc = (wg < 2048) ? 1.f : (1.f / 4096.f);
    uint4* dst = ((wg < 2048) ? (uf + (size_t)wg * 1024) : (kf + (size_t)(wg - 2048) * 1024)) + 4 * t;
    #pragma unroll
    for (int q = 0; q < 4; ++q) {
        uint4 o;
        cf2 v0 = x[PERM(4 * q)] * sc, v1 = x[PERM(4 * q + 1)] * sc;
        cf2 v2 = x[PERM(4 * q + 2)] * sc, v3 = x[PERM(4 * q + 3)] * sc;
        o.x = pack_bf2(v0.x, v0.y);
        o.y = pack_bf2(v1.x, v1.y);
        o.z = pack_bf2(v2.x, v2.y);
        o.w = pack_bf2(v3.x, v3.y);
        dst[q] = o;
    }
}

// ============================ fft_inv FUSED with gdt ============================
// spectra product in registers, DIT stages, half-out; then (fused) D-skip + gelu + fragment-major
// store of g directly from registers. XCD-chunked decode: tau = (bid&7)*1024 + bid>>3.
__global__ __launch_bounds__(256, 5) void fft_inv_kernel(
    const uint4* __restrict__ uf, const uint4* __restrict__ kf,
    const unsigned int* __restrict__ ub2, const float* __restrict__ s4D,
    ushort_t* __restrict__ gT)
{
    __shared__ cf2 S[4096];                     // exactly 32 KB -> 5 blocks/CU
    int bid = blockIdx.x, t = threadIdx.x;
    int tau = (bid & 7) * 1024 + (bid >> 3);    // bijective, 8192 % 8 == 0
    int e = tau >> 4, ch = (tau >> 2) & 3, bp = tau & 3;
    int r = ch * 512 + e;
    int tc = t >> 4, td = t & 15;
    int base = tc << 8;
    const uint4* zr = uf + (size_t)(bp * 512 + e) * 1024 + 4 * t;
    const uint4* kr = kf + (size_t)(ch * 512 + e) * 1024 + 4 * t;
    cf2 x[16];
    #pragma unroll
    for (int q = 0; q < 4; ++q) {
        uint4 a4 = zr[q], b4 = kr[q];
        x[4 * q + 0] = cmul(unpack_c(a4.x), unpack_c(b4.x));
        x[4 * q + 1] = cmul(unpack_c(a4.y), unpack_c(b4.y));
        x[4 * q + 2] = cmul(unpack_c(a4.z), unpack_c(b4.z));
        x[4 * q + 3] = cmul(unpack_c(a4.w), unpack_c(b4.w));
    }
    dft16p<1>(x);
    // store1: (B=tc, c=td, d=m) -> base + 16td + (td^m)
    int b1s = base + (td << 4);
    #pragma unroll
    for (int m = 0; m < 16; ++m) S[b1s + (td ^ m)] = x[PERM(m)];
    __syncthreads();
    // read1: (B=tc, c=j, d=td)
    #pragma unroll
    for (int j = 0; j < 16; ++j) x[j] = S[base + (j << 4) + (j ^ td)];
    tw_before<1>(x, (float)td, 1.f / 256.f);
    dft16p<1>(x);
    // store2: (B=tc, c=m, d=td)
    #pragma unroll
    for (int m = 0; m < 16; ++m) S[base + (m << 4) + (m ^ td)] = x[PERM(m)];
    __syncthreads();
    // read2: (B=j, c=tc, d=td) -> 256j + 16tc + (tc^td)
    int r2s = (tc << 4) + (tc ^ td);
    #pragma unroll
    for (int j = 0; j < 16; ++j) x[j] = S[(j << 8) + r2s];
    tw_before<1>(x, (float)t, 1.f / 4096.f);
    cf2 y[8];
    dft16_halfout<1>(x, y);

    // ---- fused gdt: y + D*u, gelu, fragment-major store (same index formula as old gdt) ----
    const float d = s4D[r];
    const unsigned int* ur = ub2 + (size_t)e * 8192 + (size_t)bp * 2048 + t;
    const size_t rpart = (size_t)(r >> 5) * 524288 + (size_t)(((r >> 3) & 3) * 128 + (r & 7));
    #pragma unroll
    for (int m = 0; m < 8; ++m) {
        int l = m * 256 + t;
        cf2 u2 = unpack_c(ur[m * 256]);
        float v0 = gelu_f(fmaf(d, u2.x, y[m].x));
        float v1 = gelu_f(fmaf(d, u2.y, y[m].y));
        int n_lo = bp * 4096 + l;                 // batch 2bp at position l; n_hi = n_lo + 2048
        size_t npart = (size_t)(n_lo >> 6) * 2048 + (size_t)(((n_lo >> 4) & 3) * 512 + (n_lo & 15) * 8);
        gT[rpart + npart]         = f2bfu(v0);
        gT[rpart + npart + 65536] = f2bfu(v1);    // +2048 in n -> +32*2048 ushorts
    }
}

// ============================ gemmF: EPI5 fragment-direct GEMM — no LDS, no barriers in K-loop ============
// Operands pre-stored fragment-major (Acomb via EPI2 epilogue, g via fused fft_inv): each lane loads its
// MFMA fragment as one coalesced global_load_dwordx4 from L2/L3. Depth-2 register pipeline.
__global__ __launch_bounds__(256) void gemmF_kernel(
    const ushort_t* __restrict__ Af, const ushort_t* __restrict__ Bf,
    ushort_t* __restrict__ Cb, const float* __restrict__ bias)
{
    __shared__ ushort_t SM[8704];                    // epilogue gate tile [128][68] only
    const int t = threadIdx.x;
    const int w = t >> 6, lane = t & 63, quad = lane >> 4, lr = lane & 15;
    const int wm = (w >> 1) * 64;
    const int by = blockIdx.y, n0 = blockIdx.x * 128;
    const int h = (w >> 1) ? (4 + by) : by;          // A row-block: rows {64by..} / {256+64by..}
    const int nb = (n0 >> 6) + (w & 1);              // B col-block of 64

    const ushort_t* Aw = Af + (size_t)h * 2048 + (size_t)lane * 8;   // + s*16384 + im*512
    const ushort_t* Bw = Bf + (size_t)nb * 2048 + (size_t)lane * 8;  // + s*524288 + in*512

    float4_t acc[4][4];
    #pragma unroll
    for (int i = 0; i < 4; ++i)
        #pragma unroll
        for (int j = 0; j < 4; ++j) { float4_t z = {0.f, 0.f, 0.f, 0.f}; acc[i][j] = z; }

    short8 a0[4], a1[4], b0[4], b1[4];

#define LDA(D, S) do { _Pragma("unroll") for (int i_ = 0; i_ < 4; ++i_) \
        D[i_] = *(const short8*)(Aw + (size_t)(S) * 16384 + i_ * 512); } while (0)
#define LDB(D, S) do { _Pragma("unroll") for (int i_ = 0; i_ < 4; ++i_) \
        D[i_] = *(const short8*)(Bw + (size_t)(S) * 524288 + i_ * 512); } while (0)
#define CMP(AA, BB) do { _Pragma("unroll") for (int im_ = 0; im_ < 4; ++im_) \
        _Pragma("unroll") for (int in_ = 0; in_ < 4; ++in_) \
            acc[im_][in_] = __builtin_amdgcn_mfma_f32_16x16x32_bf16(AA[im_], BB[in_], acc[im_][in_], 0, 0, 0); } while (0)

    LDA(a0, 0); LDB(b0, 0);
    LDA(a1, 1); LDB(b1, 1);
    for (int s = 0; s < 64; s += 2) {                // K = 2048 fixed -> 64 steps of 32
        CMP(a0, b0);
        if (s + 2 < 64) { LDA(a0, s + 2); LDB(b0, s + 2); }
        CMP(a1, b1);
        if (s + 3 < 64) { LDA(a1, s + 3); LDB(b1, s + 3); }
    }
#undef LDA
#undef LDB
#undef CMP

    // ---- gate-fused epilogue (identical math to previous EPI5) ----
    #pragma unroll
    for (int p = 0; p < 2; ++p) {
        if (p) __syncthreads();
        if ((w & 1) == p) {                          // waves owning this n-half
            #pragma unroll
            for (int im = 0; im < 4; ++im)
                #pragma unroll
                for (int in_ = 0; in_ < 4; ++in_) {
                    int nl = in_ * 16 + lr;
                    #pragma unroll
                    for (int r = 0; r < 4; ++r) {
                        int i = wm + im * 16 + quad * 4 + r;
                        int me = (i < 64) ? (64 * by + i) : (192 + 64 * by + i);
                        SM[i * 68 + nl] = f2bfu(acc[im][in_][r] + bias[me]);
                    }
                }
        }
        __syncthreads();
        int nl = t >> 2, gcb = (t & 3) * 16;
        size_t obase = (size_t)(n0 + 64 * p + nl) * 256 + 64 * by + gcb;
        short8 o0, o1;
        #pragma unroll
        for (int j = 0; j < 16; ++j) {
            int gc = gcb + j;
            float a = bf2f(SM[gc * 68 + nl]);
            float bb = bf2f(SM[(gc + 64) * 68 + nl]);
            ushort_t gv = f2bfu(tanh_f(a) * sigmoid_f(bb));
            if (j < 8) o0[j] = (short)gv; else o1[j - 8] = (short)gv;
        }
        *(short8*)(Cb + obase) = o0;
        *(short8*)(Cb + obase + 8) = o1;
    }
}

// ============================ gemm: 128Mx64N tile, global_load_lds, static dbuf (round-3) ============================
// Used for the short-K gemms (conv K=768, EPI4 K=256, prep K=512). EPI2 writes its output
// (Acomb) in A-FRAGMENT-major layout for gemmF.
template<int BSRC, int EPI>
__global__ __launch_bounds__(256, 4) void gemm_kernel(
    const ushort_t* __restrict__ A, const ushort_t* __restrict__ Bm,
    ushort_t* __restrict__ Cb, float* __restrict__ Cf,
    int M, int N, int K,
    const float* __restrict__ bias, const float* __restrict__ bias2,
    const ushort_t* __restrict__ xnb, float* __restrict__ dout)
{
    __shared__ ushort_t SM[16384];       // 2 x 8192 (32 KB)
    const int t = threadIdx.x;
    const int n0 = blockIdx.x * 64, m0 = blockIdx.y * 128;
    const int w = t >> 6, lane = t & 63, quad = lane >> 4, lr = lane & 15;
    const int wm = (w >> 1) * 64, wn = (w & 1) * 32;

    // ---- staging geometry ----
    const int srow = lane >> 2;                              // row within 16-row issue group
    const int swslot = ((lane & 3) ^ ((lane >> 3) & 3)) * 8; // pre-swizzled col slot (ushorts)
    const int r0q = w * 32 + srow;                           // A q=0 tile-row; q=1 adds 16
    int ar0 = m0 + r0q, ar1 = m0 + r0q + 16;
    const ushort_t* aSrc0 = A + (size_t)ar0 * K + swslot;
    const ushort_t* aSrc1 = A + (size_t)ar1 * K + swslot;
    const int nrow = n0 + w * 16 + srow;                     // B tile-row (one issue/wave)
    const ushort_t* bSrc;
    if (BSRC == 0) bSrc = Bm + (size_t)nrow * K + swslot;
    else           bSrc = Bm + (size_t)((nrow >> 11) * 2050 + (nrow & 2047)) * 256 + swslot;

    // wave-uniform LDS dest offsets within a buffer (ushort units; lane*16B added by HW)
    const int aD = w * 1024;             // A region [0,4096)
    const int bD = 4096 + w * 512;       // B region [4096,6144)

    float4_t acc[4][2];
    #pragma unroll
    for (int i = 0; i < 4; ++i)
        #pragma unroll
        for (int j = 0; j < 2; ++j) { float4_t z = {0.f, 0.f, 0.f, 0.f}; acc[i][j] = z; }

    const int qsw = (quad ^ ((lr >> 1) & 3)) << 3;           // read-side swizzled slot (ushorts)

#define STAGE(BUF, KK) do {                                                     \
        cp16(aSrc0 + (KK), SM + (BUF) + aD);                                    \
        cp16(aSrc1 + (KK), SM + (BUF) + aD + 512);                              \
        if (BSRC == 0) cp16(bSrc + (KK), SM + (BUF) + bD);                      \
        else cp16(bSrc + (((KK) >> 8) * 256 + ((KK) & 255)), SM + (BUF) + bD);  \
    } while (0)

#define COMPUTE(BUF) do {                                                       \
        const ushort_t* Al = SM + (BUF);                                        \
        const ushort_t* Bl = SM + (BUF) + 4096;                                 \
        short8 af[4], bfr[2];                                                   \
        _Pragma("unroll")                                                       \
        for (int im = 0; im < 4; ++im)                                          \
            af[im] = *(const short8*)&Al[(wm + im * 16 + lr) * 32 + qsw];       \
        _Pragma("unroll")                                                       \
        for (int in_ = 0; in_ < 2; ++in_)                                       \
            bfr[in_] = *(const short8*)&Bl[(wn + in_ * 16 + lr) * 32 + qsw];    \
        _Pragma("unroll")                                                       \
        for (int im = 0; im < 4; ++im)                                          \
            _Pragma("unroll")                                                   \
            for (int in_ = 0; in_ < 2; ++in_)                                   \
                acc[im][in_] = __builtin_amdgcn_mfma_f32_16x16x32_bf16(         \
                    af[im], bfr[in_], acc[im][in_], 0, 0, 0);                   \
    } while (0)

    // prologue: stage K-tile 0 into buffer 0
    STAGE(0, 0);
    __syncthreads();                             // drains vmcnt(0): tile 0 ready

    for (int kt = 0; kt < K; kt += 64) {         // K % 64 == 0 for all instantiations
        STAGE(8192, kt + 32);                    // prefetch odd tile into buf1
        COMPUTE(0);
        __syncthreads();                         // buf1 ready; buf0 reads done
        if (kt + 64 < K) STAGE(0, kt + 64);      // prefetch next even tile into buf0
        COMPUTE(8192);
        __syncthreads();                         // buf0 ready; buf1 reads done
    }
#undef STAGE
#undef COMPUTE

    #pragma unroll
    for (int im = 0; im < 4; ++im) {
        #pragma unroll
        for (int in_ = 0; in_ < 2; ++in_) {
            int n = n0 + wn + in_ * 16 + lr;
            int mb = m0 + wm + im * 16 + quad * 4;
            #pragma unroll
            for (int r = 0; r < 4; ++r) {
                int m = mb + r;
                float v = acc[im][in_][r];
                if (EPI == 0) {
                    v += bias[m];
                    ((__hip_bfloat16*)Cb)[(size_t)m * N + n] = __float2bfloat16(gelu_f(v));
                } else if (EPI == 1) {
                    v += (m == n) ? 1.0f : 0.0f;
                    ((__hip_bfloat16*)Cb)[(size_t)m * N + n] = __float2bfloat16(v);
                } else if (EPI == 2) {
                    // A-fragment-major write for gemmF:
                    // idx16 = ((s*8 + h)*4 + im)*64 + quad*16 + lr ; ushort = idx16*8 + j
                    size_t fi = ((((size_t)(n >> 5) * 8 + (m >> 6)) * 4 + ((m >> 4) & 3)) * 64
                                 + ((n >> 3) & 3) * 16 + (m & 15)) * 8 + (n & 7);
                    Cb[fi] = f2bfu(v);
                } else {
                    int bb = n >> 11, ll = n & 2047;
                    if (m < 256) {
                        v += bias[m];
                        int idx = (bb << 19) + (m << 11) + ll;
                        dout[idx] = (bf2f(xnb[idx]) + v) * 0.70710678118654752f;
                    } else {
                        v += bias2[m - 256];
                        dout[4194304 + (bb << 19) + ((m - 256) << 11) + ll] = v;
                    }
                }
            }
        }
    }
}

// ============================ launch ============================
extern "C" void kernel_launch(void* const* d_in, const int* in_sizes, int n_in,
                              void* d_out, int out_size, void* d_ws, size_t ws_size,
                              hipStream_t stream)
{
    const float* x         = (const float*)d_in[0];
    const float* original  = (const float*)d_in[1];
    const float* sn_scale  = (const float*)d_in[2];
    const float* conv_w    = (const float*)d_in[3];
    const float* conv_b    = (const float*)d_in[4];
    const float* s4_ln_g   = (const float*)d_in[5];
    const float* s4_ln_b   = (const float*)d_in[6];
    const float* s4_kernel = (const float*)d_in[7];
    const float* s4_D      = (const float*)d_in[8];
    const float* s4_out_w  = (const float*)d_in[9];
    const float* s4_out_b  = (const float*)d_in[10];
    const float* attn_v_w  = (const float*)d_in[11];
    const float* attn_v_b  = (const float*)d_in[12];
    const float* attn_o_w  = (const float*)d_in[13];
    const float* attn_o_b  = (const float*)d_in[14];
    const float* res_w     = (const float*)d_in[15];
    const float* res_b     = (const float*)d_in[16];
    const float* skip_w    = (const float*)d_in[17];
    const float* skip_b    = (const float*)d_in[18];

    char* ws = (char*)d_ws;
    __hip_bfloat16* convA = (__hip_bfloat16*)(ws + WS_CONVA);
    __hip_bfloat16* WvT   = (__hip_bfloat16*)(ws + WS_WV);
    __hip_bfloat16* WoBf  = (__hip_bfloat16*)(ws + WS_WO);
    __hip_bfloat16* W1T   = (__hip_bfloat16*)(ws + WS_W1);
    __hip_bfloat16* Wcat  = (__hip_bfloat16*)(ws + WS_WCAT);
    ushort_t* A2    = (ushort_t*)(ws + WS_A2);
    ushort_t* Acomb = (ushort_t*)(ws + WS_ACOMB);
    float* bcombp  = (float*)(ws + WS_BCOMB);
    ushort_t* xnb  = (ushort_t*)(ws + WS_XN);
    ushort_t* h0pT = (ushort_t*)(ws + WS_H0PT);
    ushort_t* hP   = (ushort_t*)(ws + WS_U);
    ushort_t* ubP  = (ushort_t*)(ws + WS_UB);
    uint4* ufP = (uint4*)(ws + WS_UF);
    uint4* kfP = (uint4*)(ws + WS_KF);
    ushort_t* gT    = (ushort_t*)(ws + WS_GTF);
    ushort_t* gateT = (ushort_t*)(ws + WS_GATET);

    // weight prep + attention-fold precompute
    wprep_kernel<<<dim3(4096), dim3(256), 0, stream>>>(conv_w, attn_v_w, attn_o_w, s4_out_w,
        res_w, skip_w, convA, WvT, WoBf, W1T, Wcat);
    gemm_kernel<0, 1><<<dim3(8, 4), dim3(256), 0, stream>>>(
        (const ushort_t*)WoBf, (const ushort_t*)WvT, A2, nullptr, 512, 512, 512,
        nullptr, nullptr, nullptr, nullptr);
    bias2_kernel<<<dim3(512), dim3(256), 0, stream>>>(
        (const __hip_bfloat16*)A2, s4_out_b, attn_o_w, attn_v_b, attn_o_b, bcombp);
    gemm_kernel<0, 2><<<dim3(32, 4), dim3(256), 0, stream>>>(
        A2, (const ushort_t*)W1T, Acomb, nullptr, 512, 2048, 512,
        nullptr, nullptr, nullptr, nullptr);

    // main pipeline
    prep_kernel<<<dim3(256), dim3(512), 0, stream>>>(x, original, sn_scale, xnb, h0pT);
    gemm_kernel<1, 0><<<dim3(256, 4), dim3(256), 0, stream>>>(
        (const ushort_t*)convA, h0pT, hP, nullptr, 512, NBL, 768,
        conv_b, nullptr, nullptr, nullptr);
    ln_kernel<<<dim3(256), dim3(512), 0, stream>>>(hP, ubP, s4_ln_g, s4_ln_b);
    fft_fwd_kernel<<<dim3(4096), dim3(256), 0, stream>>>(ubP, s4_kernel, ufP, kfP);
    fft_inv_kernel<<<dim3(8192), dim3(256), 0, stream>>>(
        ufP, kfP, (const unsigned int*)ubP, s4_D, gT);
    gemmF_kernel<<<dim3(128, 4), dim3(256), 0, stream>>>(
        (const ushort_t*)Acomb, gT, gateT, bcombp);
    gemm_kernel<0, 4><<<dim3(256, 4), dim3(256), 0, stream>>>(
        (const ushort_t*)Wcat, gateT, nullptr, nullptr, 512, NBL, 256,
        res_b, skip_b, xnb, (float*)d_out);
}

// Round 10
// 375.699 us; speedup vs baseline: 1.1745x; 1.0044x over previous
//
#include <hip/hip_runtime.h>
#include <hip/hip_bf16.h>
#include <math.h>

typedef __attribute__((ext_vector_type(8))) short short8;
typedef __attribute__((ext_vector_type(4))) float float4_t;
typedef __attribute__((ext_vector_type(2))) float cf2;   // complex (re, im) -> v_pk_* ops
typedef unsigned short ushort_t;
typedef unsigned int uint_t;

// Problem constants: B=8, C=256, L=2048, E=512, CH=4
#define NBL 16384          // B*L

// ---------------- workspace layout (bytes) ----------------
#define WS_CONVA   ((size_t)0)          // bf16 [512][768]  K reordered: k' = dk*256 + c
#define WS_WV      ((size_t)786432)     // bf16 [512][512]  Wv^T
#define WS_WO      ((size_t)1310720)    // bf16 [512][512]  Wo natural
#define WS_W1      ((size_t)1835008)    // bf16 [2048][512] s4_out_w^T
#define WS_WCAT    ((size_t)3932160)    // bf16 [512][256]
#define WS_A2      ((size_t)4194304)    // bf16 [512][512]  I + Wo@Wv
#define WS_ACOMB   ((size_t)4718592)    // bf16 FRAGMENT-major [s=k/32][h=m/64][im][lane][j] (2 MB)
#define WS_BCOMB   ((size_t)6815744)    // f32 [512]
#define WS_XN      ((size_t)6819840)    // bf16 [8][256][2048]
#define WS_H0PT    ((size_t)23597056)   // bf16 [16400][256]  padded x+orig, transposed
#define WS_U       ((size_t)31993856)   // bf16 [512][16384]  conv+gelu output h
#define WS_UF      ((size_t)65548288)   // bf162 [2048][4096] u-pair spectra (32 MB, ends 99102720)
#define WS_KF      ((size_t)99102720)   // bf162 [2048][4096] kernel spectra (pre-scaled 1/4096)
#define WS_GTF     ((size_t)132657152)  // bf16 FRAGMENT-major g [s][nb][in][lane][j] (64 MB, ends 199766016)
#define WS_GATET   ((size_t)199766016)  // bf16 [16384][256]  (ends 208154624)
#define WS_UB      ((size_t)208162816)  // bf16-pair uint [512][8192]  LN output u, end 224940032

// ---------------- fast transcendental helpers ----------------
__device__ __forceinline__ float gelu_f(float x) {
    float t = x * x;
    float a2 = x * fmaf(0.07135481627f, t, 1.59576912161f);
    return x / (1.f + __expf(-a2));
}
__device__ __forceinline__ float tanh_f(float a) {
    return 1.f - 2.f / (1.f + __expf(2.f * a));
}
__device__ __forceinline__ float sigmoid_f(float b) {
    return 1.f / (1.f + __expf(-b));
}

__device__ __forceinline__ unsigned int pack_bf2(float a, float b) {
#if __has_builtin(__builtin_amdgcn_cvt_pk_bf16_f32)
    auto v = __builtin_amdgcn_cvt_pk_bf16_f32(a, b);
    unsigned int r; __builtin_memcpy(&r, &v, 4); return r;
#else
    __hip_bfloat16 ha = __float2bfloat16(a), hb = __float2bfloat16(b);
    unsigned short ua = *(unsigned short*)&ha, ub = *(unsigned short*)&hb;
    return (unsigned int)ua | ((unsigned int)ub << 16);
#endif
}
__device__ __forceinline__ ushort_t f2bfu(float a) {
    __hip_bfloat16 h = __float2bfloat16(a);
    return *(ushort_t*)&h;
}
__device__ __forceinline__ cf2 unpack_c(unsigned int v) {
    cf2 r;
    r.x = __uint_as_float(v << 16);
    r.y = __uint_as_float(v & 0xffff0000u);
    return r;
}
__device__ __forceinline__ float bf2f(ushort_t u) {
    return __uint_as_float(((unsigned int)u) << 16);
}

// async global->LDS 16B per lane. LDS dest is WAVE-UNIFORM base + lane*16 (m104);
// global src is per-lane.
__device__ __forceinline__ void cp16(const ushort_t* g, ushort_t* l) {
    __builtin_amdgcn_global_load_lds(
        (__attribute__((address_space(1))) void*)(void*)g,
        (__attribute__((address_space(3))) void*)l, 16, 0, 0);
}

// ---------------- packed complex primitives ----------------
__device__ __forceinline__ cf2 cswap(cf2 a) { return __builtin_shufflevector(a, a, 1, 0); }
template<int SGN>
__device__ __forceinline__ cf2 cmuli(cf2 a) {
    cf2 s = cswap(a);
    return s * cf2{(float)(-SGN), (float)SGN};
}
__device__ __forceinline__ cf2 cmul(cf2 a, cf2 b) {
    cf2 t = cswap(a) * cf2{-b.y, b.y};
    return a * cf2{b.x, b.x} + t;
}
__device__ __forceinline__ cf2 cmulc(cf2 a, float wr, float wi) {
    cf2 t = cswap(a) * cf2{-wi, wi};
    return a * cf2{wr, wr} + t;
}

// ============================ weight prep ============================
__global__ __launch_bounds__(256) void wprep_kernel(
    const float* __restrict__ conv_w, const float* __restrict__ attn_v_w,
    const float* __restrict__ attn_o_w, const float* __restrict__ s4_out_w,
    const float* __restrict__ res_w, const float* __restrict__ skip_w,
    __hip_bfloat16* __restrict__ convA, __hip_bfloat16* __restrict__ WvT,
    __hip_bfloat16* __restrict__ WoBf, __hip_bfloat16* __restrict__ W1T,
    __hip_bfloat16* __restrict__ Wcat)
{
    const int N0 = 393216, N1 = 655360, N2c = 917504, N3 = 1966080, N4 = 2097152;
    for (int i = blockIdx.x * 256 + threadIdx.x; i < N4; i += gridDim.x * 256) {
        if (i < N0) {
            int m = i / 768, r = i - m * 768, dk = r >> 8, c = r & 255;
            convA[i] = __float2bfloat16(conv_w[m * 768 + c * 3 + dk]);
        } else if (i < N1) {
            int j = i - N0; int row = j >> 9, e = j & 511;
            WvT[j] = __float2bfloat16(attn_v_w[e * 512 + row]);
        } else if (i < N2c) {
            WoBf[i - N1] = __float2bfloat16(attn_o_w[i - N1]);
        } else if (i < N3) {
            int j = i - N2c; int ck = j >> 9, e = j & 511;
            W1T[j] = __float2bfloat16(s4_out_w[e * 2048 + ck]);
        } else {
            int j = i - N3; int m = j >> 8, c = j & 255;
            float v = (m < 256) ? res_w[m * 256 + c] : skip_w[(m - 256) * 256 + c];
            Wcat[j] = __float2bfloat16(v);
        }
    }
}

__global__ __launch_bounds__(256) void bias2_kernel(
    const __hip_bfloat16* __restrict__ A2, const float* __restrict__ s4_out_b,
    const float* __restrict__ attn_o_w, const float* __restrict__ attn_v_b,
    const float* __restrict__ attn_o_b, float* __restrict__ bcomb)
{
    __shared__ float red[256];
    int o = blockIdx.x, t = threadIdx.x;
    float s = 0.f;
    for (int e = t; e < 512; e += 256)
        s += __bfloat162float(A2[o * 512 + e]) * s4_out_b[e] + attn_o_w[o * 512 + e] * attn_v_b[e];
    red[t] = s; __syncthreads();
    for (int k = 128; k > 0; k >>= 1) { if (t < k) red[t] += red[t + k]; __syncthreads(); }
    if (t == 0) bcomb[o] = red[0] + attn_o_b[o];
}

// ============================ prep: RMSNorm->xn bf16, (x+orig)->h0pT via LDS tile ============================
__global__ __launch_bounds__(512) void prep_kernel(
    const float* __restrict__ x, const float* __restrict__ orig,
    const float* __restrict__ sn, ushort_t* __restrict__ xnb, ushort_t* __restrict__ h0pT)
{
    __shared__ float red[8][64];
    __shared__ ushort_t T[256 * 66];
    int blk = blockIdx.x, t = threadIdx.x;
    int lane = t & 63, cg = t >> 6;
    int b = blk >> 5, l0 = (blk & 31) << 6;
    size_t basein = (size_t)b * 524288 + l0 + lane;
    float ss = 0.f;
    for (int c = cg; c < 256; c += 8) {
        size_t idx = basein + (size_t)c * 2048;
        float xv = x[idx], ov = orig[idx];
        ss += xv * xv;
        T[c * 66 + lane] = f2bfu(xv + ov);
    }
    red[cg][lane] = ss;
    __syncthreads();
    float tot = 0.f;
    #pragma unroll
    for (int k = 0; k < 8; ++k) tot += red[k][lane];
    float inv = 1.0f / (sqrtf(tot) * 0.0625f + 1e-8f);
    __hip_bfloat16* xo = (__hip_bfloat16*)xnb;
    for (int c = cg; c < 256; c += 8) {
        size_t idx = basein + (size_t)c * 2048;
        xo[idx] = __float2bfloat16(sn[c] * x[idx] * inv);
    }
    int c2 = t & 255, half = t >> 8;
    size_t rowbase = (size_t)(b * 2050 + 1 + l0);
    for (int r = half; r < 64; r += 2)
        h0pT[(rowbase + r) * 256 + c2] = T[c2 * 66 + r];
    if ((blk & 31) == 0) {
        if (t < 256) h0pT[(size_t)(b * 2050) * 256 + t] = 0;
        else         h0pT[(size_t)(b * 2050 + 2049) * 256 + (t - 256)] = 0;
    }
}

// ============================ LayerNorm over E: bf16 h -> pair-interleaved bf16 u ============================
// u stored as uint pairs: ushort idx = e*16384 + (b>>1)*4096 + 2*l + (b&1)
__global__ __launch_bounds__(512) void ln_kernel(
    const ushort_t* __restrict__ h, ushort_t* __restrict__ ub,
    const float* __restrict__ gam, const float* __restrict__ bet)
{
    __shared__ float r1[8][64], r2[8][64];
    int blk = blockIdx.x, t = threadIdx.x;
    int lane = t & 63, og = t >> 6;
    int n = (blk << 6) + lane;
    float s1 = 0.f, s2 = 0.f;
    for (int o = og; o < 512; o += 8) { float v = bf2f(h[(size_t)o * NBL + n]); s1 += v; s2 += v * v; }
    r1[og][lane] = s1; r2[og][lane] = s2;
    __syncthreads();
    float mu = 0.f, m2 = 0.f;
    #pragma unroll
    for (int k = 0; k < 8; ++k) { mu += r1[k][lane]; m2 += r2[k][lane]; }
    mu *= (1.f / 512.f); m2 *= (1.f / 512.f);
    float rstd = rsqrtf(m2 - mu * mu + 1e-5f);
    int b = n >> 11, l = n & 2047;
    size_t sbase = (size_t)(b >> 1) * 4096 + 2 * l + (b & 1);
    for (int o = og; o < 512; o += 8) {
        size_t idx = (size_t)o * NBL + n;
        ub[(size_t)o * 16384 + sbase] = f2bfu((bf2f(h[idx]) - mu) * rstd * gam[o] + bet[o]);
    }
}

// ============================ FFT: 4096-pt radix-16 ============================
// fft_fwd uses the exact-32KB XOR layout (r9). fft_inv uses the PADDED 273/17 layout (r8):
// r9 A/B showed the XOR swizzle puts the loop index inside the address XOR -> loses ds_read/write
// immediate-offset folding -> +13% VALU work (dur 72.3->76.2, VALUBusy 75->81) with zero conflict
// gain (1.05M before AND after) and no occupancy gain (38% both). Padded-affine dominates for inv.
#define PERM(m) ((((m) & 3) << 2) | ((m) >> 2))

template<int SGN>
__device__ __forceinline__ void dft4p(cf2& a0, cf2& a1, cf2& a2, cf2& a3) {
    cf2 t0 = a0 + a2, t1 = a0 - a2, t2 = a1 + a3, t3 = a1 - a3;
    cf2 j3 = cmuli<SGN>(t3);
    a0 = t0 + t2; a2 = t0 - t2;
    a1 = t1 + j3; a3 = t1 - j3;
}
template<int SGN>
__device__ __forceinline__ void dft4p_half(cf2& a0, cf2& a1, cf2& a2, cf2& a3) {
    cf2 u0 = a0, u1 = a1;
    cf2 j1 = cmuli<SGN>(u1);
    a0 = u0 + u1; a2 = u0 - u1;
    a1 = u0 + j1; a3 = u0 - j1;
}
template<int SGN>
__device__ __forceinline__ void dft4p_out01(cf2 a0, cf2 a1, cf2 a2, cf2 a3, cf2& o0, cf2& o1) {
    cf2 t0 = a0 + a2, t1 = a0 - a2, t2 = a1 + a3, t3 = a1 - a3;
    o0 = t0 + t2;
    o1 = t1 + cmuli<SGN>(t3);
}

template<int SGN>
__device__ __forceinline__ void dft16_stepB(cf2* x) {
    const float sg = (float)SGN;
    const float C16[10] = {1.f, 0.92387953f, 0.70710678f, 0.38268343f, 0.f,
                           -0.38268343f, -0.70710678f, -0.92387953f, -1.f, -0.92387953f};
    const float S16[10] = {0.f, 0.38268343f, 0.70710678f, 0.92387953f, 1.f,
                           0.92387953f, 0.70710678f, 0.38268343f, 0.f, -0.38268343f};
    #pragma unroll
    for (int s = 1; s < 4; ++s)
        #pragma unroll
        for (int r = 1; r < 4; ++r) {
            int e = s * r;
            x[4 * s + r] = cmulc(x[4 * s + r], C16[e], sg * S16[e]);
        }
}
template<int SGN>
__device__ __forceinline__ void dft16p(cf2* x) {
    #pragma unroll
    for (int r = 0; r < 4; ++r) dft4p<SGN>(x[r], x[4 + r], x[8 + r], x[12 + r]);
    dft16_stepB<SGN>(x);
    #pragma unroll
    for (int s = 0; s < 4; ++s) dft4p<SGN>(x[4 * s], x[4 * s + 1], x[4 * s + 2], x[4 * s + 3]);
}
template<int SGN>
__device__ __forceinline__ void dft16_halfin(cf2* x) {
    #pragma unroll
    for (int r = 0; r < 4; ++r) dft4p_half<SGN>(x[r], x[4 + r], x[8 + r], x[12 + r]);
    dft16_stepB<SGN>(x);
    #pragma unroll
    for (int s = 0; s < 4; ++s) dft4p<SGN>(x[4 * s], x[4 * s + 1], x[4 * s + 2], x[4 * s + 3]);
}
template<int SGN>
__device__ __forceinline__ void dft16_halfout(cf2* x, cf2* y) {
    #pragma unroll
    for (int r = 0; r < 4; ++r) dft4p<SGN>(x[r], x[4 + r], x[8 + r], x[12 + r]);
    dft16_stepB<SGN>(x);
    #pragma unroll
    for (int s = 0; s < 4; ++s)
        dft4p_out01<SGN>(x[4 * s], x[4 * s + 1], x[4 * s + 2], x[4 * s + 3], y[s], y[4 + s]);
}

// Twiddle powers w^1..w^15 via binary tree: depth 4 (vs 14 serial). Round-7 lesson: table
// loads at per-lane stride 128B are a 64-line gather the compiler won't hoist (VALU 75->43%,
// latency-bound); keep twiddles in the VALU pipe.
template<int SGN>
__device__ __forceinline__ void tw_gen(cf2* w, float p, float invQ) {
    float s1, c1; __sincosf((float)SGN * 6.283185307179586f * p * invQ, &s1, &c1);
    w[1]  = cf2{c1, s1};
    w[2]  = cmul(w[1], w[1]);
    w[3]  = cmul(w[2], w[1]);
    w[4]  = cmul(w[2], w[2]);
    w[5]  = cmul(w[3], w[2]);
    w[6]  = cmul(w[3], w[3]);
    w[7]  = cmul(w[4], w[3]);
    w[8]  = cmul(w[4], w[4]);
    w[9]  = cmul(w[5], w[4]);
    w[10] = cmul(w[5], w[5]);
    w[11] = cmul(w[6], w[5]);
    w[12] = cmul(w[6], w[6]);
    w[13] = cmul(w[7], w[6]);
    w[14] = cmul(w[7], w[7]);
    w[15] = cmul(w[8], w[7]);
}
template<int SGN>
__device__ __forceinline__ void tw_after(cf2* x, float p, float invQ) {
    cf2 w[16];
    tw_gen<SGN>(w, p, invQ);
    #pragma unroll
    for (int m = 1; m < 16; ++m) x[PERM(m)] = cmul(x[PERM(m)], w[m]);
}
template<int SGN>
__device__ __forceinline__ void tw_before(cf2* x, float p, float invQ) {
    cf2 w[16];
    tw_gen<SGN>(w, p, invQ);
    #pragma unroll
    for (int j = 1; j < 16; ++j) x[j] = cmul(x[j], w[j]);
}

// forward: wg<2048 -> packed u-pair rows (uint pair loads); wg>=2048 -> kernel rows (f32, pre-scale 1/4096)
__global__ __launch_bounds__(256, 5) void fft_fwd_kernel(
    const ushort_t* __restrict__ ubf, const float* __restrict__ s4k,
    uint4* __restrict__ uf, uint4* __restrict__ kf)
{
    __shared__ cf2 S[4096];                     // exactly 32 KB -> 5 blocks/CU
    int wg = blockIdx.x, t = threadIdx.x;
    int tc = t >> 4, td = t & 15;
    int base = tc << 8;                         // 256*tc
    cf2 x[16];
    if (wg < 2048) {
        int bp = wg >> 9, e = wg & 511;
        const unsigned int* p0 = (const unsigned int*)ubf + (size_t)e * 8192 + (size_t)bp * 2048;
        #pragma unroll
        for (int j = 0; j < 8; ++j) x[j] = unpack_c(p0[j * 256 + t]);
    } else {
        const float* p0 = s4k + (size_t)(wg - 2048) * 2048;
        #pragma unroll
        for (int j = 0; j < 8; ++j) x[j] = cf2{p0[j * 256 + t], 0.f};
    }
    dft16_halfin<-1>(x);
    tw_after<-1>(x, (float)t, 1.f / 4096.f);
    // store1: (B=m, c=tc, d=td) -> 256m + 16tc + (tc^td)
    int s1 = (tc << 4) + (tc ^ td);
    #pragma unroll
    for (int m = 0; m < 16; ++m) S[(m << 8) + s1] = x[PERM(m)];
    __syncthreads();
    // read1: (B=tc, c=j, d=td)
    #pragma unroll
    for (int j = 0; j < 16; ++j) x[j] = S[base + (j << 4) + (j ^ td)];
    dft16p<-1>(x);
    tw_after<-1>(x, (float)td, 1.f / 256.f);
    // store2: (B=tc, c=m, d=td)
    #pragma unroll
    for (int m = 0; m < 16; ++m) S[base + (m << 4) + (m ^ td)] = x[PERM(m)];
    __syncthreads();
    // read2: (B=tc, c=td, d=j)
    int b2r = base + (td << 4);
    #pragma unroll
    for (int j = 0; j < 16; ++j) x[j] = S[b2r + (td ^ j)];
    dft16p<-1>(x);
    const float sc = (wg < 2048) ? 1.f : (1.f / 4096.f);
    uint4* dst = ((wg < 2048) ? (uf + (size_t)wg * 1024) : (kf + (size_t)(wg - 2048) * 1024)) + 4 * t;
    #pragma unroll
    for (int q = 0; q < 4; ++q) {
        uint4 o;
        cf2 v0 = x[PERM(4 * q)] * sc, v1 = x[PERM(4 * q + 1)] * sc;
        cf2 v2 = x[PERM(4 * q + 2)] * sc, v3 = x[PERM(4 * q + 3)] * sc;
        o.x = pack_bf2(v0.x, v0.y);
        o.y = pack_bf2(v1.x, v1.y);
        o.z = pack_bf2(v2.x, v2.y);
        o.w = pack_bf2(v3.x, v3.y);
        dst[q] = o;
    }
}

// ============================ fft_inv FUSED with gdt (padded-affine LDS, r8 layout) ============================
// spectra product in registers, DIT stages, half-out; then (fused) D-skip + gelu + fragment-major
// store of g directly from registers. XCD-chunked decode: tau = (bid&7)*1024 + bid>>3.
// LDS slot(B,c,d) = 273B + 17c + d: conflict-free AND affine in the loop index -> all ds_read/
// ds_write use one base register + compile-time offset immediates (the r9 XOR layout lost this).
__global__ __launch_bounds__(256) void fft_inv_kernel(
    const uint4* __restrict__ uf, const uint4* __restrict__ kf,
    const unsigned int* __restrict__ ub2, const float* __restrict__ s4D,
    ushort_t* __restrict__ gT)
{
    __shared__ cf2 S[4368];
    int bid = blockIdx.x, t = threadIdx.x;
    int tau = (bid & 7) * 1024 + (bid >> 3);    // bijective, 8192 % 8 == 0
    int e = tau >> 4, ch = (tau >> 2) & 3, bp = tau & 3;
    int r = ch * 512 + e;
    const uint4* zr = uf + (size_t)(bp * 512 + e) * 1024 + 4 * t;
    const uint4* kr = kf + (size_t)(ch * 512 + e) * 1024 + 4 * t;
    cf2 x[16];
    #pragma unroll
    for (int q = 0; q < 4; ++q) {
        uint4 a4 = zr[q], b4 = kr[q];
        x[4 * q + 0] = cmul(unpack_c(a4.x), unpack_c(b4.x));
        x[4 * q + 1] = cmul(unpack_c(a4.y), unpack_c(b4.y));
        x[4 * q + 2] = cmul(unpack_c(a4.z), unpack_c(b4.z));
        x[4 * q + 3] = cmul(unpack_c(a4.w), unpack_c(b4.w));
    }
    dft16p<1>(x);
    int b1 = 273 * (t >> 4) + 17 * (t & 15);
    #pragma unroll
    for (int m = 0; m < 16; ++m) S[b1 + m] = x[PERM(m)];
    __syncthreads();
    int b2 = 273 * (t >> 4) + (t & 15);
    #pragma unroll
    for (int j = 0; j < 16; ++j) x[j] = S[b2 + 17 * j];
    tw_before<1>(x, (float)(t & 15), 1.f / 256.f);
    dft16p<1>(x);
    #pragma unroll
    for (int m = 0; m < 16; ++m) S[b2 + 17 * m] = x[PERM(m)];
    __syncthreads();
    int b3 = 17 * (t >> 4) + (t & 15);
    #pragma unroll
    for (int j = 0; j < 16; ++j) x[j] = S[b3 + 273 * j];
    tw_before<1>(x, (float)t, 1.f / 4096.f);
    cf2 y[8];
    dft16_halfout<1>(x, y);

    // ---- fused gdt: y + D*u, gelu, fragment-major store (same index formula as old gdt) ----
    const float d = s4D[r];
    const unsigned int* ur = ub2 + (size_t)e * 8192 + (size_t)bp * 2048 + t;
    const size_t rpart = (size_t)(r >> 5) * 524288 + (size_t)(((r >> 3) & 3) * 128 + (r & 7));
    #pragma unroll
    for (int m = 0; m < 8; ++m) {
        int l = m * 256 + t;
        cf2 u2 = unpack_c(ur[m * 256]);
        float v0 = gelu_f(fmaf(d, u2.x, y[m].x));
        float v1 = gelu_f(fmaf(d, u2.y, y[m].y));
        int n_lo = bp * 4096 + l;                 // batch 2bp at position l; n_hi = n_lo + 2048
        size_t npart = (size_t)(n_lo >> 6) * 2048 + (size_t)(((n_lo >> 4) & 3) * 512 + (n_lo & 15) * 8);
        gT[rpart + npart]         = f2bfu(v0);
        gT[rpart + npart + 65536] = f2bfu(v1);    // +2048 in n -> +32*2048 ushorts
    }
}

// ============================ gemmF: EPI5 fragment-direct GEMM — no LDS, no barriers in K-loop ============
// Operands pre-stored fragment-major (Acomb via EPI2 epilogue, g via fused fft_inv): each lane loads its
// MFMA fragment as one coalesced global_load_dwordx4 from L2/L3. Depth-2 register pipeline.
__global__ __launch_bounds__(256) void gemmF_kernel(
    const ushort_t* __restrict__ Af, const ushort_t* __restrict__ Bf,
    ushort_t* __restrict__ Cb, const float* __restrict__ bias)
{
    __shared__ ushort_t SM[8704];                    // epilogue gate tile [128][68] only
    const int t = threadIdx.x;
    const int w = t >> 6, lane = t & 63, quad = lane >> 4, lr = lane & 15;
    const int wm = (w >> 1) * 64;
    const int by = blockIdx.y, n0 = blockIdx.x * 128;
    const int h = (w >> 1) ? (4 + by) : by;          // A row-block: rows {64by..} / {256+64by..}
    const int nb = (n0 >> 6) + (w & 1);              // B col-block of 64

    const ushort_t* Aw = Af + (size_t)h * 2048 + (size_t)lane * 8;   // + s*16384 + im*512
    const ushort_t* Bw = Bf + (size_t)nb * 2048 + (size_t)lane * 8;  // + s*524288 + in*512

    float4_t acc[4][4];
    #pragma unroll
    for (int i = 0; i < 4; ++i)
        #pragma unroll
        for (int j = 0; j < 4; ++j) { float4_t z = {0.f, 0.f, 0.f, 0.f}; acc[i][j] = z; }

    short8 a0[4], a1[4], b0[4], b1[4];

#define LDA(D, S) do { _Pragma("unroll") for (int i_ = 0; i_ < 4; ++i_) \
        D[i_] = *(const short8*)(Aw + (size_t)(S) * 16384 + i_ * 512); } while (0)
#define LDB(D, S) do { _Pragma("unroll") for (int i_ = 0; i_ < 4; ++i_) \
        D[i_] = *(const short8*)(Bw + (size_t)(S) * 524288 + i_ * 512); } while (0)
#define CMP(AA, BB) do { _Pragma("unroll") for (int im_ = 0; im_ < 4; ++im_) \
        _Pragma("unroll") for (int in_ = 0; in_ < 4; ++in_) \
            acc[im_][in_] = __builtin_amdgcn_mfma_f32_16x16x32_bf16(AA[im_], BB[in_], acc[im_][in_], 0, 0, 0); } while (0)

    LDA(a0, 0); LDB(b0, 0);
    LDA(a1, 1); LDB(b1, 1);
    for (int s = 0; s < 64; s += 2) {                // K = 2048 fixed -> 64 steps of 32
        CMP(a0, b0);
        if (s + 2 < 64) { LDA(a0, s + 2); LDB(b0, s + 2); }
        CMP(a1, b1);
        if (s + 3 < 64) { LDA(a1, s + 3); LDB(b1, s + 3); }
    }
#undef LDA
#undef LDB
#undef CMP

    // ---- gate-fused epilogue (identical math to previous EPI5) ----
    #pragma unroll
    for (int p = 0; p < 2; ++p) {
        if (p) __syncthreads();
        if ((w & 1) == p) {                          // waves owning this n-half
            #pragma unroll
            for (int im = 0; im < 4; ++im)
                #pragma unroll
                for (int in_ = 0; in_ < 4; ++in_) {
                    int nl = in_ * 16 + lr;
                    #pragma unroll
                    for (int r = 0; r < 4; ++r) {
                        int i = wm + im * 16 + quad * 4 + r;
                        int me = (i < 64) ? (64 * by + i) : (192 + 64 * by + i);
                        SM[i * 68 + nl] = f2bfu(acc[im][in_][r] + bias[me]);
                    }
                }
        }
        __syncthreads();
        int nl = t >> 2, gcb = (t & 3) * 16;
        size_t obase = (size_t)(n0 + 64 * p + nl) * 256 + 64 * by + gcb;
        short8 o0, o1;
        #pragma unroll
        for (int j = 0; j < 16; ++j) {
            int gc = gcb + j;
            float a = bf2f(SM[gc * 68 + nl]);
            float bb = bf2f(SM[(gc + 64) * 68 + nl]);
            ushort_t gv = f2bfu(tanh_f(a) * sigmoid_f(bb));
            if (j < 8) o0[j] = (short)gv; else o1[j - 8] = (short)gv;
        }
        *(short8*)(Cb + obase) = o0;
        *(short8*)(Cb + obase + 8) = o1;
    }
}

// ============================ gemm: 128Mx64N tile, global_load_lds, static dbuf (round-3) ============================
// Used for the short-K gemms (conv K=768, EPI4 K=256, prep K=512). EPI2 writes its output
// (Acomb) in A-FRAGMENT-major layout for gemmF.
template<int BSRC, int EPI>
__global__ __launch_bounds__(256, 4) void gemm_kernel(
    const ushort_t* __restrict__ A, const ushort_t* __restrict__ Bm,
    ushort_t* __restrict__ Cb, float* __restrict__ Cf,
    int M, int N, int K,
    const float* __restrict__ bias, const float* __restrict__ bias2,
    const ushort_t* __restrict__ xnb, float* __restrict__ dout)
{
    __shared__ ushort_t SM[16384];       // 2 x 8192 (32 KB)
    const int t = threadIdx.x;
    const int n0 = blockIdx.x * 64, m0 = blockIdx.y * 128;
    const int w = t >> 6, lane = t & 63, quad = lane >> 4, lr = lane & 15;
    const int wm = (w >> 1) * 64, wn = (w & 1) * 32;

    // ---- staging geometry ----
    const int srow = lane >> 2;                              // row within 16-row issue group
    const int swslot = ((lane & 3) ^ ((lane >> 3) & 3)) * 8; // pre-swizzled col slot (ushorts)
    const int r0q = w * 32 + srow;                           // A q=0 tile-row; q=1 adds 16
    int ar0 = m0 + r0q, ar1 = m0 + r0q + 16;
    const ushort_t* aSrc0 = A + (size_t)ar0 * K + swslot;
    const ushort_t* aSrc1 = A + (size_t)ar1 * K + swslot;
    const int nrow = n0 + w * 16 + srow;                     // B tile-row (one issue/wave)
    const ushort_t* bSrc;
    if (BSRC == 0) bSrc = Bm + (size_t)nrow * K + swslot;
    else           bSrc = Bm + (size_t)((nrow >> 11) * 2050 + (nrow & 2047)) * 256 + swslot;

    // wave-uniform LDS dest offsets within a buffer (ushort units; lane*16B added by HW)
    const int aD = w * 1024;             // A region [0,4096)
    const int bD = 4096 + w * 512;       // B region [4096,6144)

    float4_t acc[4][2];
    #pragma unroll
    for (int i = 0; i < 4; ++i)
        #pragma unroll
        for (int j = 0; j < 2; ++j) { float4_t z = {0.f, 0.f, 0.f, 0.f}; acc[i][j] = z; }

    const int qsw = (quad ^ ((lr >> 1) & 3)) << 3;           // read-side swizzled slot (ushorts)

#define STAGE(BUF, KK) do {                                                     \
        cp16(aSrc0 + (KK), SM + (BUF) + aD);                                    \
        cp16(aSrc1 + (KK), SM + (BUF) + aD + 512);                              \
        if (BSRC == 0) cp16(bSrc + (KK), SM + (BUF) + bD);                      \
        else cp16(bSrc + (((KK) >> 8) * 256 + ((KK) & 255)), SM + (BUF) + bD);  \
    } while (0)

#define COMPUTE(BUF) do {                                                       \
        const ushort_t* Al = SM + (BUF);                                        \
        const ushort_t* Bl = SM + (BUF) + 4096;                                 \
        short8 af[4], bfr[2];                                                   \
        _Pragma("unroll")                                                       \
        for (int im = 0; im < 4; ++im)                                          \
            af[im] = *(const short8*)&Al[(wm + im * 16 + lr) * 32 + qsw];       \
        _Pragma("unroll")                                                       \
        for (int in_ = 0; in_ < 2; ++in_)                                       \
            bfr[in_] = *(const short8*)&Bl[(wn + in_ * 16 + lr) * 32 + qsw];    \
        _Pragma("unroll")                                                       \
        for (int im = 0; im < 4; ++im)                                          \
            _Pragma("unroll")                                                   \
            for (int in_ = 0; in_ < 2; ++in_)                                   \
                acc[im][in_] = __builtin_amdgcn_mfma_f32_16x16x32_bf16(         \
                    af[im], bfr[in_], acc[im][in_], 0, 0, 0);                   \
    } while (0)

    // prologue: stage K-tile 0 into buffer 0
    STAGE(0, 0);
    __syncthreads();                             // drains vmcnt(0): tile 0 ready

    for (int kt = 0; kt < K; kt += 64) {         // K % 64 == 0 for all instantiations
        STAGE(8192, kt + 32);                    // prefetch odd tile into buf1
        COMPUTE(0);
        __syncthreads();                         // buf1 ready; buf0 reads done
        if (kt + 64 < K) STAGE(0, kt + 64);      // prefetch next even tile into buf0
        COMPUTE(8192);
        __syncthreads();                         // buf0 ready; buf1 reads done
    }
#undef STAGE
#undef COMPUTE

    #pragma unroll
    for (int im = 0; im < 4; ++im) {
        #pragma unroll
        for (int in_ = 0; in_ < 2; ++in_) {
            int n = n0 + wn + in_ * 16 + lr;
            int mb = m0 + wm + im * 16 + quad * 4;
            #pragma unroll
            for (int r = 0; r < 4; ++r) {
                int m = mb + r;
                float v = acc[im][in_][r];
                if (EPI == 0) {
                    v += bias[m];
                    ((__hip_bfloat16*)Cb)[(size_t)m * N + n] = __float2bfloat16(gelu_f(v));
                } else if (EPI == 1) {
                    v += (m == n) ? 1.0f : 0.0f;
                    ((__hip_bfloat16*)Cb)[(size_t)m * N + n] = __float2bfloat16(v);
                } else if (EPI == 2) {
                    // A-fragment-major write for gemmF:
                    // idx16 = ((s*8 + h)*4 + im)*64 + quad*16 + lr ; ushort = idx16*8 + j
                    size_t fi = ((((size_t)(n >> 5) * 8 + (m >> 6)) * 4 + ((m >> 4) & 3)) * 64
                                 + ((n >> 3) & 3) * 16 + (m & 15)) * 8 + (n & 7);
                    Cb[fi] = f2bfu(v);
                } else {
                    int bb = n >> 11, ll = n & 2047;
                    if (m < 256) {
                        v += bias[m];
                        int idx = (bb << 19) + (m << 11) + ll;
                        dout[idx] = (bf2f(xnb[idx]) + v) * 0.70710678118654752f;
                    } else {
                        v += bias2[m - 256];
                        dout[4194304 + (bb << 19) + ((m - 256) << 11) + ll] = v;
                    }
                }
            }
        }
    }
}

// ============================ launch ============================
extern "C" void kernel_launch(void* const* d_in, const int* in_sizes, int n_in,
                              void* d_out, int out_size, void* d_ws, size_t ws_size,
                              hipStream_t stream)
{
    const float* x         = (const float*)d_in[0];
    const float* original  = (const float*)d_in[1];
    const float* sn_scale  = (const float*)d_in[2];
    const float* conv_w    = (const float*)d_in[3];
    const float* conv_b    = (const float*)d_in[4];
    const float* s4_ln_g   = (const float*)d_in[5];
    const float* s4_ln_b   = (const float*)d_in[6];
    const float* s4_kernel = (const float*)d_in[7];
    const float* s4_D      = (const float*)d_in[8];
    const float* s4_out_w  = (const float*)d_in[9];
    const float* s4_out_b  = (const float*)d_in[10];
    const float* attn_v_w  = (const float*)d_in[11];
    const float* attn_v_b  = (const float*)d_in[12];
    const float* attn_o_w  = (const float*)d_in[13];
    const float* attn_o_b  = (const float*)d_in[14];
    const float* res_w     = (const float*)d_in[15];
    const float* res_b     = (const float*)d_in[16];
    const float* skip_w    = (const float*)d_in[17];
    const float* skip_b    = (const float*)d_in[18];

    char* ws = (char*)d_ws;
    __hip_bfloat16* convA = (__hip_bfloat16*)(ws + WS_CONVA);
    __hip_bfloat16* WvT   = (__hip_bfloat16*)(ws + WS_WV);
    __hip_bfloat16* WoBf  = (__hip_bfloat16*)(ws + WS_WO);
    __hip_bfloat16* W1T   = (__hip_bfloat16*)(ws + WS_W1);
    __hip_bfloat16* Wcat  = (__hip_bfloat16*)(ws + WS_WCAT);
    ushort_t* A2    = (ushort_t*)(ws + WS_A2);
    ushort_t* Acomb = (ushort_t*)(ws + WS_ACOMB);
    float* bcombp  = (float*)(ws + WS_BCOMB);
    ushort_t* xnb  = (ushort_t*)(ws + WS_XN);
    ushort_t* h0pT = (ushort_t*)(ws + WS_H0PT);
    ushort_t* hP   = (ushort_t*)(ws + WS_U);
    ushort_t* ubP  = (ushort_t*)(ws + WS_UB);
    uint4* ufP = (uint4*)(ws + WS_UF);
    uint4* kfP = (uint4*)(ws + WS_KF);
    ushort_t* gT    = (ushort_t*)(ws + WS_GTF);
    ushort_t* gateT = (ushort_t*)(ws + WS_GATET);

    // weight prep + attention-fold precompute
    wprep_kernel<<<dim3(4096), dim3(256), 0, stream>>>(conv_w, attn_v_w, attn_o_w, s4_out_w,
        res_w, skip_w, convA, WvT, WoBf, W1T, Wcat);
    gemm_kernel<0, 1><<<dim3(8, 4), dim3(256), 0, stream>>>(
        (const ushort_t*)WoBf, (const ushort_t*)WvT, A2, nullptr, 512, 512, 512,
        nullptr, nullptr, nullptr, nullptr);
    bias2_kernel<<<dim3(512), dim3(256), 0, stream>>>(
        (const __hip_bfloat16*)A2, s4_out_b, attn_o_w, attn_v_b, attn_o_b, bcombp);
    gemm_kernel<0, 2><<<dim3(32, 4), dim3(256), 0, stream>>>(
        A2, (const ushort_t*)W1T, Acomb, nullptr, 512, 2048, 512,
        nullptr, nullptr, nullptr, nullptr);

    // main pipeline
    prep_kernel<<<dim3(256), dim3(512), 0, stream>>>(x, original, sn_scale, xnb, h0pT);
    gemm_kernel<1, 0><<<dim3(256, 4), dim3(256), 0, stream>>>(
        (const ushort_t*)convA, h0pT, hP, nullptr, 512, NBL, 768,
        conv_b, nullptr, nullptr, nullptr);
    ln_kernel<<<dim3(256), dim3(512), 0, stream>>>(hP, ubP, s4_ln_g, s4_ln_b);
    fft_fwd_kernel<<<dim3(4096), dim3(256), 0, stream>>>(ubP, s4_kernel, ufP, kfP);
    fft_inv_kernel<<<dim3(8192), dim3(256), 0, stream>>>(
        ufP, kfP, (const unsigned int*)ubP, s4_D, gT);
    gemmF_kernel<<<dim3(128, 4), dim3(256), 0, stream>>>(
        (const ushort_t*)Acomb, gT, gateT, bcombp);
    gemm_kernel<0, 4><<<dim3(256, 4), dim3(256), 0, stream>>>(
        (const ushort_t*)Wcat, gateT, nullptr, nullptr, 512, NBL, 256,
        res_b, skip_b, xnb, (float*)d_out);
}